// Round 8
// baseline (532.436 us; speedup 1.0000x reference)
//
#include <hip/hip_runtime.h>
#include <hip/hip_bf16.h>

typedef __attribute__((ext_vector_type(8))) short bf16x8;
typedef __attribute__((ext_vector_type(4))) float f32x4;

static constexpr int Tt = 2048;   // seq len
static constexpr int Cc = 1024;   // channels
static constexpr int Dd = 64;     // head dim
static constexpr int Mm = 8192;   // B*T
static constexpr int PK = 36;     // Ps LDS row stride (halfs): 72B rows, <=2-way conflicts

static constexpr size_t XN = (size_t)Mm * Cc;   // 8388608
static constexpr size_t WN = (size_t)Cc * Cc;   // 1048576
static constexpr int LSN = 4 * 16 * Tt;         // 131072 lsum entries

__device__ __forceinline__ void async_copy16(void* lds, const void* g) {
  __builtin_amdgcn_global_load_lds(
      (const __attribute__((address_space(1))) void*)g,
      (__attribute__((address_space(3))) void*)lds, 16, 0, 0);
}

__device__ __forceinline__ unsigned short f2bf(float f) {
  union { float f; unsigned int u; } v; v.f = f;
  unsigned int r = (v.u + 0x7fffu + ((v.u >> 16) & 1u)) >> 16;
  return (unsigned short)r;
}
__device__ __forceinline__ unsigned int pack2bf(float f0, float f1) {
  unsigned int b0 = __float_as_uint(f0) + 0x8000u;
  unsigned int b1 = __float_as_uint(f1) + 0x8000u;
  return (b1 & 0xffff0000u) | (b0 >> 16);
}
__device__ __forceinline__ uint4 ldconv_f32(const float* p) {
  float4 lo = *(const float4*)p;
  float4 hi = *(const float4*)(p + 4);
  uint4 r;
  r.x = pack2bf(lo.x, lo.y);
  r.y = pack2bf(lo.z, lo.w);
  r.z = pack2bf(hi.x, hi.y);
  r.w = pack2bf(hi.z, hi.w);
  return r;
}
__device__ __forceinline__ uint4 ldconv_scale(const float* p, float s) {
  float4 lo = *(const float4*)p;
  float4 hi = *(const float4*)(p + 4);
  uint4 r;
  r.x = pack2bf(lo.x * s, lo.y * s);
  r.y = pack2bf(lo.z * s, lo.w * s);
  r.z = pack2bf(hi.x * s, hi.y * s);
  r.w = pack2bf(hi.z * s, hi.w * s);
  return r;
}

// f32 -> bf16 pre-convert of X, Wq, Wk, Wv into d_out scratch (23.1MB < 33.5MB).
__global__ __launch_bounds__(256) void convert_all(
    const float* __restrict__ x, const float* __restrict__ wq,
    const float* __restrict__ wk, const float* __restrict__ wv,
    unsigned short* __restrict__ dst)
{
  const size_t i = ((size_t)blockIdx.x * 256 + threadIdx.x) * 8;
  const float* s; size_t off;
  if (i < XN)                { s = x;  off = 0; }
  else if (i < XN + WN)      { s = wq; off = XN; }
  else if (i < XN + 2 * WN)  { s = wk; off = XN + WN; }
  else                       { s = wv; off = XN + 2 * WN; }
  *(uint4*)(dst + i) = ldconv_f32(s + (i - off));
}

// NT GEMM, all-bf16 inputs, m97-pattern global_load_lds staging.
// MODE 0: bf16 out[m*Cc+n]*mult+bias. MODE 1 (V): bf16 out[(b*Cc+n)*Tt+t].
template <int MODE>
__device__ __forceinline__ void gemm_async_body(
    unsigned short* As, unsigned short* Bs,
    const unsigned short* __restrict__ A,
    const unsigned short* __restrict__ Bt,
    const float* __restrict__ bias,
    unsigned short* __restrict__ out, float mult)
{
  const int tid  = threadIdx.x;
  const int wave = tid >> 6;
  const int lane = tid & 63;
  const int m16  = lane & 15;
  const int quad = lane >> 4;
  const int row0 = blockIdx.x * 128;
  const int col0 = blockIdx.y * 128;
  const int wm = (wave >> 1) * 64;
  const int wn = (wave & 1) * 64;

  f32x4 acc[4][4] = {};

  const int c0 = tid, c1 = 256 + tid;
  const unsigned short* Ag0 = A  + (size_t)(row0 + (c0 >> 2)) * Cc + (c0 & 3) * 8;
  const unsigned short* Ag1 = A  + (size_t)(row0 + (c1 >> 2)) * Cc + (c1 & 3) * 8;
  const unsigned short* Bg0 = Bt + (size_t)(col0 + (c0 >> 2)) * Cc + (c0 & 3) * 8;
  const unsigned short* Bg1 = Bt + (size_t)(col0 + (c1 >> 2)) * Cc + (c1 & 3) * 8;
  char* Al0 = (char*)As + wave * 1024;
  char* Al1 = (char*)As + 4096 + wave * 1024;
  char* Bl0 = (char*)Bs + wave * 1024;
  char* Bl1 = (char*)Bs + 4096 + wave * 1024;

  for (int k0 = 0; k0 < Cc; k0 += 32) {
    __syncthreads();
    async_copy16(Al0, Ag0 + k0);
    async_copy16(Al1, Ag1 + k0);
    async_copy16(Bl0, Bg0 + k0);
    async_copy16(Bl1, Bg1 + k0);
    __syncthreads();
    bf16x8 af[4], bfr[4];
#pragma unroll
    for (int i = 0; i < 4; ++i)
      af[i] = *(const bf16x8*)(As + (wm + i * 16 + m16) * 32 + quad * 8);
#pragma unroll
    for (int j = 0; j < 4; ++j)
      bfr[j] = *(const bf16x8*)(Bs + (wn + j * 16 + m16) * 32 + quad * 8);
#pragma unroll
    for (int i = 0; i < 4; ++i)
#pragma unroll
      for (int j = 0; j < 4; ++j)
        acc[i][j] = __builtin_amdgcn_mfma_f32_16x16x32_bf16(af[i], bfr[j], acc[i][j], 0, 0, 0);
  }

#pragma unroll
  for (int i = 0; i < 4; ++i) {
    const int rbase = row0 + wm + i * 16 + quad * 4;
#pragma unroll
    for (int j = 0; j < 4; ++j) {
      const int col = col0 + wn + j * 16 + m16;
      const float bv = bias[col];
      if (MODE == 0) {
#pragma unroll
        for (int r = 0; r < 4; ++r)
          out[(size_t)(rbase + r) * Cc + col] = f2bf((acc[i][j][r] + bv) * mult);
      } else {
        const int t0 = rbase & (Tt - 1);
        const int b  = rbase >> 11;
        ushort4 pk;
        pk.x = f2bf(acc[i][j][0] + bv);
        pk.y = f2bf(acc[i][j][1] + bv);
        pk.z = f2bf(acc[i][j][2] + bv);
        pk.w = f2bf(acc[i][j][3] + bv);
        *(ushort4*)(out + (size_t)(b * Cc + col) * Tt + t0) = pk;
      }
    }
  }
}

__global__ __launch_bounds__(256) void qkv_gemm(
    const unsigned short* __restrict__ Xb,
    const unsigned short* __restrict__ Wqb, const float* __restrict__ bq,
    const unsigned short* __restrict__ Wkb, const float* __restrict__ bk,
    const unsigned short* __restrict__ Wvb, const float* __restrict__ bv,
    unsigned short* Qw, unsigned short* Kw, unsigned short* Vtw)
{
  __shared__ __align__(16) unsigned short smem[8192];
  const int z = blockIdx.z;
  // Q scale folds 1/sqrt(d) AND log2(e) so attention uses exp2 directly.
  if (z == 0)      gemm_async_body<0>(smem, smem + 4096, Xb, Wqb, bq, Qw, 0.125f * 1.44269504f);
  else if (z == 1) gemm_async_body<0>(smem, smem + 4096, Xb, Wkb, bk, Kw, 1.0f);
  else             gemm_async_body<1>(smem, smem + 4096, Xb, Wvb, bv, Vtw, 1.0f);
}

// Split-K flash attention, barrier-free. One WAVE = one (32-row strip, <=8-tile
// key chunk) job. K/V fragments load directly from global (B-operand layout is
// 16B-contiguous in K row-major and Vt). Partials combined by f32 atomicAdd
// (valid because softmax uses fixed m=0 — unnormalized exp sums add exactly).
__global__ __launch_bounds__(256, 4) void attn_split(
    const unsigned short* __restrict__ Q,
    const unsigned short* __restrict__ Kg,
    const unsigned short* __restrict__ Vt,
    float* __restrict__ Yf, float* __restrict__ lsumBuf)
{
  __shared__ __align__(16) unsigned short Ps[4 * 2 * 2 * 16 * PK]; // per-wave regions

  const int tid  = threadIdx.x;
  const int wave = tid >> 6;
  const int lane = tid & 63;
  const int m16  = lane & 15;
  const int quad = lane >> 4;

  const int sidx = 63 - blockIdx.x;           // strip id, heavy first
  const int bh = blockIdx.y;
  const int b = bh >> 4, h = bh & 15;
  const int qw = sidx * 32;
  const int nk = (sidx >> 1) + 1;             // tiles needed by this strip
  const int chunks = (nk + 7) >> 3;
  const int c = wave;                          // wave = key-chunk
  if (c >= chunks) return;                     // idle wave exits (no barriers anywhere)
  const int ktBeg = c * 8;
  const int ktEnd = min(ktBeg + 8, nk);

  const unsigned short* Qb = Q + (size_t)(b * Tt + qw) * Cc + h * Dd;
  bf16x8 qf[2][2];
#pragma unroll
  for (int s = 0; s < 2; ++s)
#pragma unroll
    for (int kk = 0; kk < 2; ++kk)
      qf[s][kk] = *(const bf16x8*)(Qb + (size_t)(s * 16 + m16) * Cc + kk * 32 + quad * 8);

  f32x4 o[2][4] = {};
  float lsum[2][4] = {};

  const unsigned short* Kb = Kg + (size_t)(b * Tt) * Cc + h * Dd;
  const unsigned short* Vb = Vt + (size_t)(b * Cc + h * Dd) * Tt;
  unsigned short* PsW = Ps + (size_t)wave * (2 * 2 * 16 * PK);

  for (int kt = ktBeg; kt < ktEnd; ++kt) {
    const int k0 = kt * 64;
    // K fragments (B-operand): lane m16 -> key jn*16+m16, k = kk*32+quad*8+j.
    bf16x8 kf[2][4];
#pragma unroll
    for (int kk = 0; kk < 2; ++kk)
#pragma unroll
      for (int jn = 0; jn < 4; ++jn)
        kf[kk][jn] = *(const bf16x8*)(Kb + (size_t)(k0 + jn * 16 + m16) * Cc + kk * 32 + quad * 8);

#pragma unroll
    for (int s = 0; s < 2; ++s) {
      const int smin = qw + s * 16;
      if (k0 > smin + 15) continue;            // tile fully masked for this strip (uniform)
      f32x4 sv[4] = {};
#pragma unroll
      for (int kk = 0; kk < 2; ++kk)
#pragma unroll
        for (int jn = 0; jn < 4; ++jn)
          sv[jn] = __builtin_amdgcn_mfma_f32_16x16x32_bf16(qf[s][kk], kf[kk][jn], sv[jn], 0, 0, 0);

      if (k0 + 63 <= smin) {                   // fully unmasked tile: bare exp2
#pragma unroll
        for (int r = 0; r < 4; ++r)
#pragma unroll
          for (int jn = 0; jn < 4; ++jn) {
            const float p = __builtin_exp2f(sv[jn][r]);
            sv[jn][r] = p;
            lsum[s][r] += p;
          }
      } else {                                  // diagonal tile: causal mask
        const int qb = smin + quad * 4;
#pragma unroll
        for (int r = 0; r < 4; ++r) {
          const int qa = qb + r;
#pragma unroll
          for (int jn = 0; jn < 4; ++jn) {
            const bool masked = (k0 + jn * 16 + m16 > qa);
            const float p = masked ? 0.f : __builtin_exp2f(sv[jn][r]);
            sv[jn][r] = p;
            lsum[s][r] += p;
          }
        }
      }
      // P: C-layout -> per-wave LDS -> A-layout
#pragma unroll
      for (int jn = 0; jn < 4; ++jn)
#pragma unroll
        for (int r = 0; r < 4; ++r)
          PsW[(s * 2 + (jn >> 1)) * 16 * PK + (quad * 4 + r) * PK + (jn & 1) * 16 + m16]
              = f2bf(sv[jn][r]);
    }

    // V fragments (B-operand): lane m16 -> dd jn*16+m16, k = key kk*32+quad*8+j.
    bf16x8 vf[2][4];
#pragma unroll
    for (int kk = 0; kk < 2; ++kk)
#pragma unroll
      for (int jn = 0; jn < 4; ++jn)
        vf[kk][jn] = *(const bf16x8*)(Vb + (size_t)(jn * 16 + m16) * Tt + k0 + kk * 32 + quad * 8);

    asm volatile("s_waitcnt lgkmcnt(0)" ::: "memory");  // Ps round-trip (wave-local)
#pragma unroll
    for (int s = 0; s < 2; ++s) {
      if (k0 > qw + s * 16 + 15) continue;
      bf16x8 pf[2];
#pragma unroll
      for (int kk = 0; kk < 2; ++kk)
        pf[kk] = *(const bf16x8*)(PsW + (s * 2 + kk) * 16 * PK + m16 * PK + quad * 8);
#pragma unroll
      for (int kk = 0; kk < 2; ++kk)
#pragma unroll
        for (int jn = 0; jn < 4; ++jn)
          o[s][jn] = __builtin_amdgcn_mfma_f32_16x16x32_bf16(pf[kk], vf[kk][jn], o[s][jn], 0, 0, 0);
    }
  }

  // combine: unnormalized O and l via device-scope f32 atomics
#pragma unroll
  for (int s = 0; s < 2; ++s)
#pragma unroll
    for (int r = 0; r < 4; ++r) {
      float l = lsum[s][r];
#pragma unroll
      for (int off = 1; off < 16; off <<= 1)
        l += __shfl_xor(l, off, 64);
      const int t = qw + s * 16 + quad * 4 + r;
      if (m16 == 0)
        atomicAdd(lsumBuf + (size_t)(b * 16 + h) * Tt + t, l);
      float* yp = Yf + (size_t)(b * Tt + t) * Cc + h * Dd;
#pragma unroll
      for (int jn = 0; jn < 4; ++jn)
        atomicAdd(yp + jn * 16 + m16, o[s][jn][r]);
    }
}

__global__ __launch_bounds__(256) void inv_k(float* __restrict__ l) {
  const int i = blockIdx.x * 256 + threadIdx.x;
  if (i < LSN) {
    const float v = l[i];
    l[i] = (v > 0.f) ? (1.0f / v) : 0.f;
  }
}

// proj: A = Yf f32 (register-convert staging with per-row/head invL scale),
// B = Wp f32 (register-convert), f32 out. Prefetch pipeline.
__global__ __launch_bounds__(256) void proj_gemm(
    const float* __restrict__ Yf, const float* __restrict__ invL,
    const float* __restrict__ Wp, const float* __restrict__ bp,
    float* __restrict__ out)
{
  __shared__ __align__(16) unsigned short As[4096];
  __shared__ __align__(16) unsigned short Bs[4096];
  const int tid  = threadIdx.x;
  const int wave = tid >> 6;
  const int lane = tid & 63;
  const int m16  = lane & 15;
  const int quad = lane >> 4;
  const int row0 = blockIdx.x * 128;
  const int col0 = blockIdx.y * 128;
  const int wm = (wave >> 1) * 64;
  const int wn = (wave & 1) * 64;

  f32x4 acc[4][4] = {};

  const int c0 = tid, c1 = 256 + tid;
  const int r0 = row0 + (c0 >> 2), r1 = row0 + (c1 >> 2);
  const float* Af0 = Yf + (size_t)r0 * Cc + (c0 & 3) * 8;
  const float* Af1 = Yf + (size_t)r1 * Cc + (c1 & 3) * 8;
  const float* Bg0 = Wp + (size_t)(col0 + (c0 >> 2)) * Cc + (c0 & 3) * 8;
  const float* Bg1 = Wp + (size_t)(col0 + (c1 >> 2)) * Cc + (c1 & 3) * 8;
  const int t0 = r0 & (Tt - 1), b0i = r0 >> 11;
  const int t1 = r1 & (Tt - 1), b1i = r1 >> 11;
  // h = k0>>6 is uniform per slab: col base = k0 + ch*8, ch*8 <= 24 < 64-gap.
  const float* iL0 = invL + (size_t)b0i * 16 * Tt + t0;
  const float* iL1 = invL + (size_t)b1i * 16 * Tt + t1;

  uint4 a0 = ldconv_scale(Af0, iL0[0]);
  uint4 a1 = ldconv_scale(Af1, iL1[0]);
  uint4 b0 = ldconv_f32(Bg0);
  uint4 b1 = ldconv_f32(Bg1);

  for (int k0 = 0; k0 < Cc; k0 += 32) {
    __syncthreads();
    *(uint4*)(As + (size_t)c0 * 8) = a0;
    *(uint4*)(As + (size_t)c1 * 8) = a1;
    *(uint4*)(Bs + (size_t)c0 * 8) = b0;
    *(uint4*)(Bs + (size_t)c1 * 8) = b1;
    __syncthreads();
    if (k0 + 32 < Cc) {
      const int kn = k0 + 32;
      const int hn = kn >> 6;
      a0 = ldconv_scale(Af0 + kn, iL0[(size_t)hn * Tt]);
      a1 = ldconv_scale(Af1 + kn, iL1[(size_t)hn * Tt]);
      b0 = ldconv_f32(Bg0 + kn);
      b1 = ldconv_f32(Bg1 + kn);
    }
    bf16x8 af[4], bfr[4];
#pragma unroll
    for (int i = 0; i < 4; ++i)
      af[i] = *(const bf16x8*)(As + (wm + i * 16 + m16) * 32 + quad * 8);
#pragma unroll
    for (int j = 0; j < 4; ++j)
      bfr[j] = *(const bf16x8*)(Bs + (wn + j * 16 + m16) * 32 + quad * 8);
#pragma unroll
    for (int i = 0; i < 4; ++i)
#pragma unroll
      for (int j = 0; j < 4; ++j)
        acc[i][j] = __builtin_amdgcn_mfma_f32_16x16x32_bf16(af[i], bfr[j], acc[i][j], 0, 0, 0);
  }

#pragma unroll
  for (int i = 0; i < 4; ++i) {
    const int rbase = row0 + wm + i * 16 + quad * 4;
#pragma unroll
    for (int j = 0; j < 4; ++j) {
      const int col = col0 + wn + j * 16 + m16;
      const float bv = bp[col];
#pragma unroll
      for (int r = 0; r < 4; ++r)
        out[(size_t)(rbase + r) * Cc + col] = acc[i][j][r] + bv;
    }
  }
}

extern "C" void kernel_launch(void* const* d_in, const int* in_sizes, int n_in,
                              void* d_out, int out_size, void* d_ws, size_t ws_size,
                              hipStream_t stream)
{
  const float* x  = (const float*)d_in[0];
  const float* Wq = (const float*)d_in[1];
  const float* bq = (const float*)d_in[2];
  const float* Wk = (const float*)d_in[3];
  const float* bk = (const float*)d_in[4];
  const float* Wv = (const float*)d_in[5];
  const float* bv = (const float*)d_in[6];
  const float* Wp = (const float*)d_in[7];
  const float* bp = (const float*)d_in[8];

  unsigned short* ws  = (unsigned short*)d_ws;
  unsigned short* Qw  = ws;                          // bf16 [8192][1024] (scale folded)
  unsigned short* Kw  = ws + (size_t)1 * XN;         // bf16 [8192][1024]
  unsigned short* Vtw = ws + (size_t)2 * XN;         // bf16 [b*1024 + n][2048]
  float* Yf   = (float*)(ws + (size_t)3 * XN);       // f32 [8192][1024] unnormalized O
  float* lsum = Yf + XN;                             // f32 [4][16][2048]

  // d_out doubles as bf16 scratch for converted X/Wq/Wk/Wv; proj overwrites last.
  unsigned short* cvt = (unsigned short*)d_out;
  unsigned short* Xb  = cvt;
  unsigned short* Wqb = cvt + XN;
  unsigned short* Wkb = cvt + XN + WN;
  unsigned short* Wvb = cvt + XN + 2 * WN;
  float* out = (float*)d_out;

  (void)hipMemsetAsync(Yf, 0, (XN + LSN) * sizeof(float), stream);  // atomics need zeros
  convert_all<<<5632, 256, 0, stream>>>(x, Wq, Wk, Wv, cvt);
  qkv_gemm<<<dim3(64, 8, 3), 256, 0, stream>>>(Xb, Wqb, bq, Wkb, bk, Wvb, bv, Qw, Kw, Vtw);
  attn_split<<<dim3(64, 64), 256, 0, stream>>>(Qw, Kw, Vtw, Yf, lsum);
  inv_k<<<512, 256, 0, stream>>>(lsum);
  proj_gemm<<<dim3(64, 8), 256, 0, stream>>>(Yf, lsum, Wp, bp, out);
}

// Round 9
// 466.657 us; speedup vs baseline: 1.1410x; 1.1410x over previous
//
#include <hip/hip_runtime.h>
#include <hip/hip_bf16.h>

typedef __attribute__((ext_vector_type(8))) short bf16x8;
typedef __attribute__((ext_vector_type(4))) float f32x4;

static constexpr int Tt = 2048;   // seq len
static constexpr int Cc = 1024;   // channels
static constexpr int Dd = 64;     // head dim
static constexpr int Mm = 8192;   // B*T
static constexpr int PK = 36;     // Ps LDS row stride (halfs): 72B rows, <=2-way conflicts

static constexpr size_t XN = (size_t)Mm * Cc;   // 8388608
static constexpr size_t WN = (size_t)Cc * Cc;   // 1048576

__device__ __forceinline__ void async_copy16(void* lds, const void* g) {
  __builtin_amdgcn_global_load_lds(
      (const __attribute__((address_space(1))) void*)g,
      (__attribute__((address_space(3))) void*)lds, 16, 0, 0);
}

__device__ __forceinline__ unsigned short f2bf(float f) {
  union { float f; unsigned int u; } v; v.f = f;
  unsigned int r = (v.u + 0x7fffu + ((v.u >> 16) & 1u)) >> 16;
  return (unsigned short)r;
}
__device__ __forceinline__ unsigned int pack2bf(float f0, float f1) {
  unsigned int b0 = __float_as_uint(f0) + 0x8000u;
  unsigned int b1 = __float_as_uint(f1) + 0x8000u;
  return (b1 & 0xffff0000u) | (b0 >> 16);
}
__device__ __forceinline__ uint4 ldconv_f32(const float* p) {
  float4 lo = *(const float4*)p;
  float4 hi = *(const float4*)(p + 4);
  uint4 r;
  r.x = pack2bf(lo.x, lo.y);
  r.y = pack2bf(lo.z, lo.w);
  r.z = pack2bf(hi.x, hi.y);
  r.w = pack2bf(hi.z, hi.w);
  return r;
}

// f32 -> bf16 pre-convert of X, Wq, Wk, Wv into d_out scratch (23.1MB < 33.5MB).
__global__ __launch_bounds__(256) void convert_all(
    const float* __restrict__ x, const float* __restrict__ wq,
    const float* __restrict__ wk, const float* __restrict__ wv,
    unsigned short* __restrict__ dst)
{
  const size_t i = ((size_t)blockIdx.x * 256 + threadIdx.x) * 8;
  const float* s; size_t off;
  if (i < XN)                { s = x;  off = 0; }
  else if (i < XN + WN)      { s = wq; off = XN; }
  else if (i < XN + 2 * WN)  { s = wk; off = XN + WN; }
  else                       { s = wv; off = XN + 2 * WN; }
  *(uint4*)(dst + i) = ldconv_f32(s + (i - off));
}

// NT GEMM, all-bf16 inputs, m97-pattern global_load_lds staging.
// MODE 0: bf16 out[m*Cc+n]*mult+bias. MODE 1 (V): bf16 out[(b*Cc+n)*Tt+t].
template <int MODE>
__device__ __forceinline__ void gemm_async_body(
    unsigned short* As, unsigned short* Bs,
    const unsigned short* __restrict__ A,
    const unsigned short* __restrict__ Bt,
    const float* __restrict__ bias,
    unsigned short* __restrict__ out, float mult)
{
  const int tid  = threadIdx.x;
  const int wave = tid >> 6;
  const int lane = tid & 63;
  const int m16  = lane & 15;
  const int quad = lane >> 4;
  const int row0 = blockIdx.x * 128;
  const int col0 = blockIdx.y * 128;
  const int wm = (wave >> 1) * 64;
  const int wn = (wave & 1) * 64;

  f32x4 acc[4][4] = {};

  const int c0 = tid, c1 = 256 + tid;
  const unsigned short* Ag0 = A  + (size_t)(row0 + (c0 >> 2)) * Cc + (c0 & 3) * 8;
  const unsigned short* Ag1 = A  + (size_t)(row0 + (c1 >> 2)) * Cc + (c1 & 3) * 8;
  const unsigned short* Bg0 = Bt + (size_t)(col0 + (c0 >> 2)) * Cc + (c0 & 3) * 8;
  const unsigned short* Bg1 = Bt + (size_t)(col0 + (c1 >> 2)) * Cc + (c1 & 3) * 8;
  char* Al0 = (char*)As + wave * 1024;
  char* Al1 = (char*)As + 4096 + wave * 1024;
  char* Bl0 = (char*)Bs + wave * 1024;
  char* Bl1 = (char*)Bs + 4096 + wave * 1024;

  for (int k0 = 0; k0 < Cc; k0 += 32) {
    __syncthreads();
    async_copy16(Al0, Ag0 + k0);
    async_copy16(Al1, Ag1 + k0);
    async_copy16(Bl0, Bg0 + k0);
    async_copy16(Bl1, Bg1 + k0);
    __syncthreads();
    bf16x8 af[4], bfr[4];
#pragma unroll
    for (int i = 0; i < 4; ++i)
      af[i] = *(const bf16x8*)(As + (wm + i * 16 + m16) * 32 + quad * 8);
#pragma unroll
    for (int j = 0; j < 4; ++j)
      bfr[j] = *(const bf16x8*)(Bs + (wn + j * 16 + m16) * 32 + quad * 8);
#pragma unroll
    for (int i = 0; i < 4; ++i)
#pragma unroll
      for (int j = 0; j < 4; ++j)
        acc[i][j] = __builtin_amdgcn_mfma_f32_16x16x32_bf16(af[i], bfr[j], acc[i][j], 0, 0, 0);
  }

#pragma unroll
  for (int i = 0; i < 4; ++i) {
    const int rbase = row0 + wm + i * 16 + quad * 4;
#pragma unroll
    for (int j = 0; j < 4; ++j) {
      const int col = col0 + wn + j * 16 + m16;
      const float bv = bias[col];
      if (MODE == 0) {
#pragma unroll
        for (int r = 0; r < 4; ++r)
          out[(size_t)(rbase + r) * Cc + col] = f2bf((acc[i][j][r] + bv) * mult);
      } else {
        const int t0 = rbase & (Tt - 1);
        const int b  = rbase >> 11;
        ushort4 pk;
        pk.x = f2bf(acc[i][j][0] + bv);
        pk.y = f2bf(acc[i][j][1] + bv);
        pk.z = f2bf(acc[i][j][2] + bv);
        pk.w = f2bf(acc[i][j][3] + bv);
        *(ushort4*)(out + (size_t)(b * Cc + col) * Tt + t0) = pk;
      }
    }
  }
}

__global__ __launch_bounds__(256) void qkv_gemm(
    const unsigned short* __restrict__ Xb,
    const unsigned short* __restrict__ Wqb, const float* __restrict__ bq,
    const unsigned short* __restrict__ Wkb, const float* __restrict__ bk,
    const unsigned short* __restrict__ Wvb, const float* __restrict__ bv,
    unsigned short* Qw, unsigned short* Kw, unsigned short* Vtw)
{
  __shared__ __align__(16) unsigned short smem[8192];
  const int z = blockIdx.z;
  // Q scale folds 1/sqrt(d) AND log2(e) so attention uses exp2 directly.
  if (z == 0)      gemm_async_body<0>(smem, smem + 4096, Xb, Wqb, bq, Qw, 0.125f * 1.44269504f);
  else if (z == 1) gemm_async_body<0>(smem, smem + 4096, Xb, Wkb, bk, Kw, 1.0f);
  else             gemm_async_body<1>(smem, smem + 4096, Xb, Wvb, bv, Vtw, 1.0f);
}

// Wave-per-strip flash attention, barrier-free, atomic-free.
// One WAVE owns one whole 32-row strip (all its key tiles) -> private (O,l),
// normalized bf16 write. Static complementary scheduling: strip sidx costs
// (sidx>>1)+1 tiles; block p's 4 waves take {63-2p, 2p, 62-2p, 2p+1} =
// exactly 66 tiles per block -> uniform makespan at 4 blocks/CU.
// K/V fragments load directly from global (B-operand layout is 16B-contiguous).
__global__ __launch_bounds__(256, 4) void attn_wave(
    const unsigned short* __restrict__ Q,
    const unsigned short* __restrict__ Kg,
    const unsigned short* __restrict__ Vt,
    unsigned short* __restrict__ Y)
{
  __shared__ __align__(16) unsigned short Ps[4 * 2 * 2 * 16 * PK]; // per-wave regions

  const int tid  = threadIdx.x;
  const int wave = tid >> 6;
  const int lane = tid & 63;
  const int m16  = lane & 15;
  const int quad = lane >> 4;

  const int p  = blockIdx.x;                  // 0..15
  const int bh = blockIdx.y;
  const int b = bh >> 4, h = bh & 15;
  // waves: 0 -> 63-2p (heavy), 1 -> 2p (light), 2 -> 62-2p, 3 -> 2p+1
  const int sidx = (wave & 1) ? (2 * p + (wave >> 1)) : (63 - 2 * p - (wave >> 1));
  const int qw = sidx * 32;
  const int nk = (sidx >> 1) + 1;             // tiles for this strip

  const unsigned short* Qb = Q + (size_t)(b * Tt + qw) * Cc + h * Dd;
  bf16x8 qf[2][2];
#pragma unroll
  for (int s = 0; s < 2; ++s)
#pragma unroll
    for (int kk = 0; kk < 2; ++kk)
      qf[s][kk] = *(const bf16x8*)(Qb + (size_t)(s * 16 + m16) * Cc + kk * 32 + quad * 8);

  f32x4 o[2][4] = {};
  float lsum[2][4] = {};

  const unsigned short* Kb = Kg + (size_t)(b * Tt) * Cc + h * Dd;
  const unsigned short* Vb = Vt + (size_t)(b * Cc + h * Dd) * Tt;
  unsigned short* PsW = Ps + (size_t)wave * (2 * 2 * 16 * PK);

  for (int kt = 0; kt < nk; ++kt) {
    const int k0 = kt * 64;
    // K fragments (B-operand): lane m16 -> key jn*16+m16, k = kk*32+quad*8+j.
    bf16x8 kf[2][4];
#pragma unroll
    for (int kk = 0; kk < 2; ++kk)
#pragma unroll
      for (int jn = 0; jn < 4; ++jn)
        kf[kk][jn] = *(const bf16x8*)(Kb + (size_t)(k0 + jn * 16 + m16) * Cc + kk * 32 + quad * 8);

#pragma unroll
    for (int s = 0; s < 2; ++s) {
      const int smin = qw + s * 16;
      if (k0 > smin + 15) continue;            // tile fully masked for this sub-strip
      f32x4 sv[4] = {};
#pragma unroll
      for (int kk = 0; kk < 2; ++kk)
#pragma unroll
        for (int jn = 0; jn < 4; ++jn)
          sv[jn] = __builtin_amdgcn_mfma_f32_16x16x32_bf16(qf[s][kk], kf[kk][jn], sv[jn], 0, 0, 0);

      if (k0 + 63 <= smin) {                   // fully unmasked tile: bare exp2
#pragma unroll
        for (int r = 0; r < 4; ++r)
#pragma unroll
          for (int jn = 0; jn < 4; ++jn) {
            const float pv = __builtin_exp2f(sv[jn][r]);
            sv[jn][r] = pv;
            lsum[s][r] += pv;
          }
      } else {                                  // diagonal tile: causal mask
        const int qb = smin + quad * 4;
#pragma unroll
        for (int r = 0; r < 4; ++r) {
          const int qa = qb + r;
#pragma unroll
          for (int jn = 0; jn < 4; ++jn) {
            const bool masked = (k0 + jn * 16 + m16 > qa);
            const float pv = masked ? 0.f : __builtin_exp2f(sv[jn][r]);
            sv[jn][r] = pv;
            lsum[s][r] += pv;
          }
        }
      }
      // P: C-layout -> per-wave LDS -> A-layout
#pragma unroll
      for (int jn = 0; jn < 4; ++jn)
#pragma unroll
        for (int r = 0; r < 4; ++r)
          PsW[(s * 2 + (jn >> 1)) * 16 * PK + (quad * 4 + r) * PK + (jn & 1) * 16 + m16]
              = f2bf(sv[jn][r]);
    }

    // V fragments (B-operand): lane m16 -> dd jn*16+m16, k = key kk*32+quad*8+j.
    bf16x8 vf[2][4];
#pragma unroll
    for (int kk = 0; kk < 2; ++kk)
#pragma unroll
      for (int jn = 0; jn < 4; ++jn)
        vf[kk][jn] = *(const bf16x8*)(Vb + (size_t)(jn * 16 + m16) * Tt + k0 + kk * 32 + quad * 8);

    asm volatile("s_waitcnt lgkmcnt(0)" ::: "memory");  // Ps round-trip (wave-local)
#pragma unroll
    for (int s = 0; s < 2; ++s) {
      if (k0 > qw + s * 16 + 15) continue;
      bf16x8 pf[2];
#pragma unroll
      for (int kk = 0; kk < 2; ++kk)
        pf[kk] = *(const bf16x8*)(PsW + (s * 2 + kk) * 16 * PK + m16 * PK + quad * 8);
#pragma unroll
      for (int kk = 0; kk < 2; ++kk)
#pragma unroll
        for (int jn = 0; jn < 4; ++jn)
          o[s][jn] = __builtin_amdgcn_mfma_f32_16x16x32_bf16(pf[kk], vf[kk][jn], o[s][jn], 0, 0, 0);
    }
  }

  // wave-private normalization + bf16 output (no atomics)
#pragma unroll
  for (int s = 0; s < 2; ++s)
#pragma unroll
    for (int r = 0; r < 4; ++r) {
      float l = lsum[s][r];
#pragma unroll
      for (int off = 1; off < 16; off <<= 1)
        l += __shfl_xor(l, off, 64);
      const float inv = (l > 0.f) ? (1.0f / l) : 0.f;
      const int t = qw + s * 16 + quad * 4 + r;
      unsigned short* yp = Y + (size_t)(b * Tt + t) * Cc + h * Dd;
#pragma unroll
      for (int jn = 0; jn < 4; ++jn)
        yp[jn * 16 + m16] = f2bf(o[s][jn][r] * inv);
    }
}

// proj: A = Yw bf16 (async staging), B = Wp f32 (register-convert), f32 out.
__global__ __launch_bounds__(256) void proj_gemm(
    const unsigned short* __restrict__ Y,
    const float* __restrict__ Wp, const float* __restrict__ bp,
    float* __restrict__ out)
{
  __shared__ __align__(16) unsigned short As[4096];
  __shared__ __align__(16) unsigned short Bs[4096];
  const int tid  = threadIdx.x;
  const int wave = tid >> 6;
  const int lane = tid & 63;
  const int m16  = lane & 15;
  const int quad = lane >> 4;
  const int row0 = blockIdx.x * 128;
  const int col0 = blockIdx.y * 128;
  const int wm = (wave >> 1) * 64;
  const int wn = (wave & 1) * 64;

  f32x4 acc[4][4] = {};

  const int c0 = tid, c1 = 256 + tid;
  const unsigned short* Ag0 = Y + (size_t)(row0 + (c0 >> 2)) * Cc + (c0 & 3) * 8;
  const unsigned short* Ag1 = Y + (size_t)(row0 + (c1 >> 2)) * Cc + (c1 & 3) * 8;
  const float* Bg0 = Wp + (size_t)(col0 + (c0 >> 2)) * Cc + (c0 & 3) * 8;
  const float* Bg1 = Wp + (size_t)(col0 + (c1 >> 2)) * Cc + (c1 & 3) * 8;
  char* Al0 = (char*)As + wave * 1024;
  char* Al1 = (char*)As + 4096 + wave * 1024;

  uint4 b0 = ldconv_f32(Bg0);
  uint4 b1 = ldconv_f32(Bg1);

  for (int k0 = 0; k0 < Cc; k0 += 32) {
    __syncthreads();
    async_copy16(Al0, Ag0 + k0);
    async_copy16(Al1, Ag1 + k0);
    *(uint4*)(Bs + (size_t)c0 * 8) = b0;
    *(uint4*)(Bs + (size_t)c1 * 8) = b1;
    __syncthreads();
    if (k0 + 32 < Cc) {
      b0 = ldconv_f32(Bg0 + k0 + 32);
      b1 = ldconv_f32(Bg1 + k0 + 32);
    }
    bf16x8 af[4], bfr[4];
#pragma unroll
    for (int i = 0; i < 4; ++i)
      af[i] = *(const bf16x8*)(As + (wm + i * 16 + m16) * 32 + quad * 8);
#pragma unroll
    for (int j = 0; j < 4; ++j)
      bfr[j] = *(const bf16x8*)(Bs + (wn + j * 16 + m16) * 32 + quad * 8);
#pragma unroll
    for (int i = 0; i < 4; ++i)
#pragma unroll
      for (int j = 0; j < 4; ++j)
        acc[i][j] = __builtin_amdgcn_mfma_f32_16x16x32_bf16(af[i], bfr[j], acc[i][j], 0, 0, 0);
  }

#pragma unroll
  for (int i = 0; i < 4; ++i) {
    const int rbase = row0 + wm + i * 16 + quad * 4;
#pragma unroll
    for (int j = 0; j < 4; ++j) {
      const int col = col0 + wn + j * 16 + m16;
      const float bv = bp[col];
#pragma unroll
      for (int r = 0; r < 4; ++r)
        out[(size_t)(rbase + r) * Cc + col] = acc[i][j][r] + bv;
    }
  }
}

extern "C" void kernel_launch(void* const* d_in, const int* in_sizes, int n_in,
                              void* d_out, int out_size, void* d_ws, size_t ws_size,
                              hipStream_t stream)
{
  const float* x  = (const float*)d_in[0];
  const float* Wq = (const float*)d_in[1];
  const float* bq = (const float*)d_in[2];
  const float* Wk = (const float*)d_in[3];
  const float* bk = (const float*)d_in[4];
  const float* Wv = (const float*)d_in[5];
  const float* bv = (const float*)d_in[6];
  const float* Wp = (const float*)d_in[7];
  const float* bp = (const float*)d_in[8];

  unsigned short* ws  = (unsigned short*)d_ws;
  unsigned short* Qw  = ws;                          // bf16 [8192][1024] (scale folded)
  unsigned short* Kw  = ws + (size_t)1 * XN;         // bf16 [8192][1024]
  unsigned short* Vtw = ws + (size_t)2 * XN;         // bf16 [b*1024 + n][2048]
  unsigned short* Yw  = ws + (size_t)3 * XN;         // bf16 [8192][1024]

  // d_out doubles as bf16 scratch for converted X/Wq/Wk/Wv; proj overwrites last.
  unsigned short* cvt = (unsigned short*)d_out;
  unsigned short* Xb  = cvt;
  unsigned short* Wqb = cvt + XN;
  unsigned short* Wkb = cvt + XN + WN;
  unsigned short* Wvb = cvt + XN + 2 * WN;
  float* out = (float*)d_out;

  convert_all<<<5632, 256, 0, stream>>>(x, Wq, Wk, Wv, cvt);
  qkv_gemm<<<dim3(64, 8, 3), 256, 0, stream>>>(Xb, Wqb, bq, Wkb, bk, Wvb, bv, Qw, Kw, Vtw);
  attn_wave<<<dim3(16, 64), 256, 0, stream>>>(Qw, Kw, Vtw, Yw);
  proj_gemm<<<dim3(64, 8), 256, 0, stream>>>(Yw, Wp, bp, out);
}

// Round 10
// 337.758 us; speedup vs baseline: 1.5764x; 1.3816x over previous
//
#include <hip/hip_runtime.h>
#include <hip/hip_bf16.h>

typedef __attribute__((ext_vector_type(8))) short bf16x8;
typedef __attribute__((ext_vector_type(4))) float f32x4;

static constexpr int Tt = 2048;   // seq len
static constexpr int Cc = 1024;   // channels
static constexpr int Dd = 64;     // head dim
static constexpr int Mm = 8192;   // B*T
static constexpr int PK = 36;     // Ps LDS row stride (halfs): 72B rows, <=2-way conflicts

static constexpr size_t XN = (size_t)Mm * Cc;   // 8388608
static constexpr size_t WN = (size_t)Cc * Cc;   // 1048576

__device__ __forceinline__ void async_copy16(void* lds, const void* g) {
  __builtin_amdgcn_global_load_lds(
      (const __attribute__((address_space(1))) void*)g,
      (__attribute__((address_space(3))) void*)lds, 16, 0, 0);
}

__device__ __forceinline__ unsigned short f2bf(float f) {
  union { float f; unsigned int u; } v; v.f = f;
  unsigned int r = (v.u + 0x7fffu + ((v.u >> 16) & 1u)) >> 16;
  return (unsigned short)r;
}
__device__ __forceinline__ unsigned int pack2bf(float f0, float f1) {
  unsigned int b0 = __float_as_uint(f0) + 0x8000u;
  unsigned int b1 = __float_as_uint(f1) + 0x8000u;
  return (b1 & 0xffff0000u) | (b0 >> 16);
}
__device__ __forceinline__ uint4 ldconv_f32(const float* p) {
  float4 lo = *(const float4*)p;
  float4 hi = *(const float4*)(p + 4);
  uint4 r;
  r.x = pack2bf(lo.x, lo.y);
  r.y = pack2bf(lo.z, lo.w);
  r.z = pack2bf(hi.x, hi.y);
  r.w = pack2bf(hi.z, hi.w);
  return r;
}

// f32 -> bf16 pre-convert of X, Wq, Wk, Wv into d_out scratch (23.1MB < 33.5MB).
__global__ __launch_bounds__(256) void convert_all(
    const float* __restrict__ x, const float* __restrict__ wq,
    const float* __restrict__ wk, const float* __restrict__ wv,
    unsigned short* __restrict__ dst)
{
  const size_t i = ((size_t)blockIdx.x * 256 + threadIdx.x) * 8;
  const float* s; size_t off;
  if (i < XN)                { s = x;  off = 0; }
  else if (i < XN + WN)      { s = wq; off = XN; }
  else if (i < XN + 2 * WN)  { s = wk; off = XN + WN; }
  else                       { s = wv; off = XN + 2 * WN; }
  *(uint4*)(dst + i) = ldconv_f32(s + (i - off));
}

// NT GEMM, all-bf16 inputs, m97-pattern global_load_lds staging.
// MODE 0: bf16 out[m*Cc+n]*mult+bias. MODE 1 (V): bf16 out[(b*Cc+n)*Tt+t].
template <int MODE>
__device__ __forceinline__ void gemm_async_body(
    unsigned short* As, unsigned short* Bs,
    const unsigned short* __restrict__ A,
    const unsigned short* __restrict__ Bt,
    const float* __restrict__ bias,
    unsigned short* __restrict__ out, float mult)
{
  const int tid  = threadIdx.x;
  const int wave = tid >> 6;
  const int lane = tid & 63;
  const int m16  = lane & 15;
  const int quad = lane >> 4;
  const int row0 = blockIdx.x * 128;
  const int col0 = blockIdx.y * 128;
  const int wm = (wave >> 1) * 64;
  const int wn = (wave & 1) * 64;

  f32x4 acc[4][4] = {};

  const int c0 = tid, c1 = 256 + tid;
  const unsigned short* Ag0 = A  + (size_t)(row0 + (c0 >> 2)) * Cc + (c0 & 3) * 8;
  const unsigned short* Ag1 = A  + (size_t)(row0 + (c1 >> 2)) * Cc + (c1 & 3) * 8;
  const unsigned short* Bg0 = Bt + (size_t)(col0 + (c0 >> 2)) * Cc + (c0 & 3) * 8;
  const unsigned short* Bg1 = Bt + (size_t)(col0 + (c1 >> 2)) * Cc + (c1 & 3) * 8;
  char* Al0 = (char*)As + wave * 1024;
  char* Al1 = (char*)As + 4096 + wave * 1024;
  char* Bl0 = (char*)Bs + wave * 1024;
  char* Bl1 = (char*)Bs + 4096 + wave * 1024;

  for (int k0 = 0; k0 < Cc; k0 += 32) {
    __syncthreads();
    async_copy16(Al0, Ag0 + k0);
    async_copy16(Al1, Ag1 + k0);
    async_copy16(Bl0, Bg0 + k0);
    async_copy16(Bl1, Bg1 + k0);
    __syncthreads();
    bf16x8 af[4], bfr[4];
#pragma unroll
    for (int i = 0; i < 4; ++i)
      af[i] = *(const bf16x8*)(As + (wm + i * 16 + m16) * 32 + quad * 8);
#pragma unroll
    for (int j = 0; j < 4; ++j)
      bfr[j] = *(const bf16x8*)(Bs + (wn + j * 16 + m16) * 32 + quad * 8);
#pragma unroll
    for (int i = 0; i < 4; ++i)
#pragma unroll
      for (int j = 0; j < 4; ++j)
        acc[i][j] = __builtin_amdgcn_mfma_f32_16x16x32_bf16(af[i], bfr[j], acc[i][j], 0, 0, 0);
  }

#pragma unroll
  for (int i = 0; i < 4; ++i) {
    const int rbase = row0 + wm + i * 16 + quad * 4;
#pragma unroll
    for (int j = 0; j < 4; ++j) {
      const int col = col0 + wn + j * 16 + m16;
      const float bv = bias[col];
      if (MODE == 0) {
#pragma unroll
        for (int r = 0; r < 4; ++r)
          out[(size_t)(rbase + r) * Cc + col] = f2bf((acc[i][j][r] + bv) * mult);
      } else {
        const int t0 = rbase & (Tt - 1);
        const int b  = rbase >> 11;
        ushort4 pk;
        pk.x = f2bf(acc[i][j][0] + bv);
        pk.y = f2bf(acc[i][j][1] + bv);
        pk.z = f2bf(acc[i][j][2] + bv);
        pk.w = f2bf(acc[i][j][3] + bv);
        *(ushort4*)(out + (size_t)(b * Cc + col) * Tt + t0) = pk;
      }
    }
  }
}

__global__ __launch_bounds__(256) void qkv_gemm(
    const unsigned short* __restrict__ Xb,
    const unsigned short* __restrict__ Wqb, const float* __restrict__ bq,
    const unsigned short* __restrict__ Wkb, const float* __restrict__ bk,
    const unsigned short* __restrict__ Wvb, const float* __restrict__ bv,
    unsigned short* Qw, unsigned short* Kw, unsigned short* Vtw)
{
  __shared__ __align__(16) unsigned short smem[8192];
  const int z = blockIdx.z;
  // Q scale folds 1/sqrt(d) AND log2(e) so attention uses exp2 directly.
  if (z == 0)      gemm_async_body<0>(smem, smem + 4096, Xb, Wqb, bq, Qw, 0.125f * 1.44269504f);
  else if (z == 1) gemm_async_body<0>(smem, smem + 4096, Xb, Wkb, bk, Kw, 1.0f);
  else             gemm_async_body<1>(smem, smem + 4096, Xb, Wvb, bv, Vtw, 1.0f);
}

// Wave-per-strip-PAIR flash attention, barrier-free, atomic-free, spill-free.
// One WAVE owns the complementary pair (sidx, 63-sidx): (sidx>>1)+1 +
// (32-(sidx>>1)) = exactly 33 tiles for EVERY wave -> perfect static balance.
// Each strip processed sequentially with private (O,l); normalized bf16 write.
// NO __launch_bounds__ occupancy cap: the wave needs ~120 VGPRs; capping at 64
// (round 8/9) spilled fragments to scratch -> 351MB of scratch writes.
__global__ __launch_bounds__(256) void attn_pair(
    const unsigned short* __restrict__ Q,
    const unsigned short* __restrict__ Kg,
    const unsigned short* __restrict__ Vt,
    unsigned short* __restrict__ Y)
{
  __shared__ __align__(16) unsigned short Ps[4 * 2 * 2 * 16 * PK]; // per-wave regions

  const int tid  = threadIdx.x;
  const int wave = tid >> 6;
  const int lane = tid & 63;
  const int m16  = lane & 15;
  const int quad = lane >> 4;

  const int pr = blockIdx.x;                  // 0..7
  const int bh = blockIdx.y;
  const int b = bh >> 4, h = bh & 15;
  const int pj = pr * 4 + wave;               // pair id 0..31

  const unsigned short* Kb = Kg + (size_t)(b * Tt) * Cc + h * Dd;
  const unsigned short* Vb = Vt + (size_t)(b * Cc + h * Dd) * Tt;
  unsigned short* PsW = Ps + (size_t)wave * (2 * 2 * 16 * PK);

  for (int half = 0; half < 2; ++half) {
    const int sidx = half ? pj : (63 - pj);   // heavy strip first
    const int qw = sidx * 32;
    const int nk = (sidx >> 1) + 1;           // tiles for this strip

    const unsigned short* Qb = Q + (size_t)(b * Tt + qw) * Cc + h * Dd;
    bf16x8 qf[2][2];
#pragma unroll
    for (int s = 0; s < 2; ++s)
#pragma unroll
      for (int kk = 0; kk < 2; ++kk)
        qf[s][kk] = *(const bf16x8*)(Qb + (size_t)(s * 16 + m16) * Cc + kk * 32 + quad * 8);

    f32x4 o[2][4] = {};
    float lsum[2][4] = {};

    for (int kt = 0; kt < nk; ++kt) {
      const int k0 = kt * 64;
      // K fragments (B-operand): lane m16 -> key jn*16+m16, k = kk*32+quad*8+j.
      bf16x8 kf[2][4];
#pragma unroll
      for (int kk = 0; kk < 2; ++kk)
#pragma unroll
        for (int jn = 0; jn < 4; ++jn)
          kf[kk][jn] = *(const bf16x8*)(Kb + (size_t)(k0 + jn * 16 + m16) * Cc + kk * 32 + quad * 8);

#pragma unroll
      for (int s = 0; s < 2; ++s) {
        const int smin = qw + s * 16;
        if (k0 > smin + 15) continue;          // tile fully masked for this sub-strip
        f32x4 sv[4] = {};
#pragma unroll
        for (int kk = 0; kk < 2; ++kk)
#pragma unroll
          for (int jn = 0; jn < 4; ++jn)
            sv[jn] = __builtin_amdgcn_mfma_f32_16x16x32_bf16(qf[s][kk], kf[kk][jn], sv[jn], 0, 0, 0);

        if (k0 + 63 <= smin) {                 // fully unmasked tile: bare exp2
#pragma unroll
          for (int r = 0; r < 4; ++r)
#pragma unroll
            for (int jn = 0; jn < 4; ++jn) {
              const float pv = __builtin_exp2f(sv[jn][r]);
              sv[jn][r] = pv;
              lsum[s][r] += pv;
            }
        } else {                                // diagonal tile: causal mask
          const int qb = smin + quad * 4;
#pragma unroll
          for (int r = 0; r < 4; ++r) {
            const int qa = qb + r;
#pragma unroll
            for (int jn = 0; jn < 4; ++jn) {
              const bool masked = (k0 + jn * 16 + m16 > qa);
              const float pv = masked ? 0.f : __builtin_exp2f(sv[jn][r]);
              sv[jn][r] = pv;
              lsum[s][r] += pv;
            }
          }
        }
        // P: C-layout -> per-wave LDS -> A-layout
#pragma unroll
        for (int jn = 0; jn < 4; ++jn)
#pragma unroll
          for (int r = 0; r < 4; ++r)
            PsW[(s * 2 + (jn >> 1)) * 16 * PK + (quad * 4 + r) * PK + (jn & 1) * 16 + m16]
                = f2bf(sv[jn][r]);
      }

      // V fragments (B-operand): lane m16 -> dd jn*16+m16, k = key kk*32+quad*8+j.
      bf16x8 vf[2][4];
#pragma unroll
      for (int kk = 0; kk < 2; ++kk)
#pragma unroll
        for (int jn = 0; jn < 4; ++jn)
          vf[kk][jn] = *(const bf16x8*)(Vb + (size_t)(jn * 16 + m16) * Tt + k0 + kk * 32 + quad * 8);

      asm volatile("s_waitcnt lgkmcnt(0)" ::: "memory");  // Ps round-trip (wave-local)
#pragma unroll
      for (int s = 0; s < 2; ++s) {
        if (k0 > qw + s * 16 + 15) continue;
        bf16x8 pf[2];
#pragma unroll
        for (int kk = 0; kk < 2; ++kk)
          pf[kk] = *(const bf16x8*)(PsW + (s * 2 + kk) * 16 * PK + m16 * PK + quad * 8);
#pragma unroll
        for (int kk = 0; kk < 2; ++kk)
#pragma unroll
          for (int jn = 0; jn < 4; ++jn)
            o[s][jn] = __builtin_amdgcn_mfma_f32_16x16x32_bf16(pf[kk], vf[kk][jn], o[s][jn], 0, 0, 0);
      }
    }

    // wave-private normalization + bf16 output (no atomics)
#pragma unroll
    for (int s = 0; s < 2; ++s)
#pragma unroll
      for (int r = 0; r < 4; ++r) {
        float l = lsum[s][r];
#pragma unroll
        for (int off = 1; off < 16; off <<= 1)
          l += __shfl_xor(l, off, 64);
        const float inv = (l > 0.f) ? (1.0f / l) : 0.f;
        const int t = qw + s * 16 + quad * 4 + r;
        unsigned short* yp = Y + (size_t)(b * Tt + t) * Cc + h * Dd;
#pragma unroll
        for (int jn = 0; jn < 4; ++jn)
          yp[jn * 16 + m16] = f2bf(o[s][jn][r] * inv);
      }
  }
}

// proj: A = Yw bf16 (async staging), B = Wp f32 (register-convert), f32 out.
__global__ __launch_bounds__(256) void proj_gemm(
    const unsigned short* __restrict__ Y,
    const float* __restrict__ Wp, const float* __restrict__ bp,
    float* __restrict__ out)
{
  __shared__ __align__(16) unsigned short As[4096];
  __shared__ __align__(16) unsigned short Bs[4096];
  const int tid  = threadIdx.x;
  const int wave = tid >> 6;
  const int lane = tid & 63;
  const int m16  = lane & 15;
  const int quad = lane >> 4;
  const int row0 = blockIdx.x * 128;
  const int col0 = blockIdx.y * 128;
  const int wm = (wave >> 1) * 64;
  const int wn = (wave & 1) * 64;

  f32x4 acc[4][4] = {};

  const int c0 = tid, c1 = 256 + tid;
  const unsigned short* Ag0 = Y + (size_t)(row0 + (c0 >> 2)) * Cc + (c0 & 3) * 8;
  const unsigned short* Ag1 = Y + (size_t)(row0 + (c1 >> 2)) * Cc + (c1 & 3) * 8;
  const float* Bg0 = Wp + (size_t)(col0 + (c0 >> 2)) * Cc + (c0 & 3) * 8;
  const float* Bg1 = Wp + (size_t)(col0 + (c1 >> 2)) * Cc + (c1 & 3) * 8;
  char* Al0 = (char*)As + wave * 1024;
  char* Al1 = (char*)As + 4096 + wave * 1024;

  uint4 b0 = ldconv_f32(Bg0);
  uint4 b1 = ldconv_f32(Bg1);

  for (int k0 = 0; k0 < Cc; k0 += 32) {
    __syncthreads();
    async_copy16(Al0, Ag0 + k0);
    async_copy16(Al1, Ag1 + k0);
    *(uint4*)(Bs + (size_t)c0 * 8) = b0;
    *(uint4*)(Bs + (size_t)c1 * 8) = b1;
    __syncthreads();
    if (k0 + 32 < Cc) {
      b0 = ldconv_f32(Bg0 + k0 + 32);
      b1 = ldconv_f32(Bg1 + k0 + 32);
    }
    bf16x8 af[4], bfr[4];
#pragma unroll
    for (int i = 0; i < 4; ++i)
      af[i] = *(const bf16x8*)(As + (wm + i * 16 + m16) * 32 + quad * 8);
#pragma unroll
    for (int j = 0; j < 4; ++j)
      bfr[j] = *(const bf16x8*)(Bs + (wn + j * 16 + m16) * 32 + quad * 8);
#pragma unroll
    for (int i = 0; i < 4; ++i)
#pragma unroll
      for (int j = 0; j < 4; ++j)
        acc[i][j] = __builtin_amdgcn_mfma_f32_16x16x32_bf16(af[i], bfr[j], acc[i][j], 0, 0, 0);
  }

#pragma unroll
  for (int i = 0; i < 4; ++i) {
    const int rbase = row0 + wm + i * 16 + quad * 4;
#pragma unroll
    for (int j = 0; j < 4; ++j) {
      const int col = col0 + wn + j * 16 + m16;
      const float bv = bp[col];
#pragma unroll
      for (int r = 0; r < 4; ++r)
        out[(size_t)(rbase + r) * Cc + col] = acc[i][j][r] + bv;
    }
  }
}

extern "C" void kernel_launch(void* const* d_in, const int* in_sizes, int n_in,
                              void* d_out, int out_size, void* d_ws, size_t ws_size,
                              hipStream_t stream)
{
  const float* x  = (const float*)d_in[0];
  const float* Wq = (const float*)d_in[1];
  const float* bq = (const float*)d_in[2];
  const float* Wk = (const float*)d_in[3];
  const float* bk = (const float*)d_in[4];
  const float* Wv = (const float*)d_in[5];
  const float* bv = (const float*)d_in[6];
  const float* Wp = (const float*)d_in[7];
  const float* bp = (const float*)d_in[8];

  unsigned short* ws  = (unsigned short*)d_ws;
  unsigned short* Qw  = ws;                          // bf16 [8192][1024] (scale folded)
  unsigned short* Kw  = ws + (size_t)1 * XN;         // bf16 [8192][1024]
  unsigned short* Vtw = ws + (size_t)2 * XN;         // bf16 [b*1024 + n][2048]
  unsigned short* Yw  = ws + (size_t)3 * XN;         // bf16 [8192][1024]

  // d_out doubles as bf16 scratch for converted X/Wq/Wk/Wv; proj overwrites last.
  unsigned short* cvt = (unsigned short*)d_out;
  unsigned short* Xb  = cvt;
  unsigned short* Wqb = cvt + XN;
  unsigned short* Wkb = cvt + XN + WN;
  unsigned short* Wvb = cvt + XN + 2 * WN;
  float* out = (float*)d_out;

  convert_all<<<5632, 256, 0, stream>>>(x, Wq, Wk, Wv, cvt);
  qkv_gemm<<<dim3(64, 8, 3), 256, 0, stream>>>(Xb, Wqb, bq, Wkb, bk, Wvb, bv, Qw, Kw, Vtw);
  attn_pair<<<dim3(8, 64), 256, 0, stream>>>(Qw, Kw, Vtw, Yw);
  proj_gemm<<<dim3(64, 8), 256, 0, stream>>>(Yw, Wp, bp, out);
}

// Round 11
// 317.367 us; speedup vs baseline: 1.6777x; 1.0643x over previous
//
#include <hip/hip_runtime.h>
#include <hip/hip_bf16.h>

typedef __attribute__((ext_vector_type(8))) short bf16x8;
typedef __attribute__((ext_vector_type(4))) float f32x4;

static constexpr int Tt = 2048;   // seq len
static constexpr int Cc = 1024;   // channels
static constexpr int Dd = 64;     // head dim
static constexpr int Mm = 8192;   // B*T
static constexpr int PK = 36;     // Ps LDS row stride (halfs): 72B rows, <=2-way conflicts

static constexpr size_t XN = (size_t)Mm * Cc;   // 8388608
static constexpr size_t WN = (size_t)Cc * Cc;   // 1048576

__device__ __forceinline__ void async_copy16(void* lds, const void* g) {
  __builtin_amdgcn_global_load_lds(
      (const __attribute__((address_space(1))) void*)g,
      (__attribute__((address_space(3))) void*)lds, 16, 0, 0);
}

__device__ __forceinline__ unsigned short f2bf(float f) {
  union { float f; unsigned int u; } v; v.f = f;
  unsigned int r = (v.u + 0x7fffu + ((v.u >> 16) & 1u)) >> 16;
  return (unsigned short)r;
}
__device__ __forceinline__ unsigned int pack2bf(float f0, float f1) {
  unsigned int b0 = __float_as_uint(f0) + 0x8000u;
  unsigned int b1 = __float_as_uint(f1) + 0x8000u;
  return (b1 & 0xffff0000u) | (b0 >> 16);
}
__device__ __forceinline__ uint4 ldconv_f32(const float* p) {
  float4 lo = *(const float4*)p;
  float4 hi = *(const float4*)(p + 4);
  uint4 r;
  r.x = pack2bf(lo.x, lo.y);
  r.y = pack2bf(lo.z, lo.w);
  r.z = pack2bf(hi.x, hi.y);
  r.w = pack2bf(hi.z, hi.w);
  return r;
}

// f32 -> bf16 pre-convert of X, Wq, Wk, Wv into d_out scratch (23.1MB < 33.5MB).
__global__ __launch_bounds__(256) void convert_all(
    const float* __restrict__ x, const float* __restrict__ wq,
    const float* __restrict__ wk, const float* __restrict__ wv,
    unsigned short* __restrict__ dst)
{
  const size_t i = ((size_t)blockIdx.x * 256 + threadIdx.x) * 8;
  const float* s; size_t off;
  if (i < XN)                { s = x;  off = 0; }
  else if (i < XN + WN)      { s = wq; off = XN; }
  else if (i < XN + 2 * WN)  { s = wk; off = XN + WN; }
  else                       { s = wv; off = XN + 2 * WN; }
  *(uint4*)(dst + i) = ldconv_f32(s + (i - off));
}

// NT GEMM, all-bf16 inputs, m97-pattern global_load_lds staging.
// MODE 0: bf16 out[m*Cc+n]*mult+bias. MODE 1 (V): bf16 out[(b*Cc+n)*Tt+t].
template <int MODE>
__device__ __forceinline__ void gemm_async_body(
    unsigned short* As, unsigned short* Bs,
    const unsigned short* __restrict__ A,
    const unsigned short* __restrict__ Bt,
    const float* __restrict__ bias,
    unsigned short* __restrict__ out, float mult)
{
  const int tid  = threadIdx.x;
  const int wave = tid >> 6;
  const int lane = tid & 63;
  const int m16  = lane & 15;
  const int quad = lane >> 4;
  const int row0 = blockIdx.x * 128;
  const int col0 = blockIdx.y * 128;
  const int wm = (wave >> 1) * 64;
  const int wn = (wave & 1) * 64;

  f32x4 acc[4][4] = {};

  const int c0 = tid, c1 = 256 + tid;
  const unsigned short* Ag0 = A  + (size_t)(row0 + (c0 >> 2)) * Cc + (c0 & 3) * 8;
  const unsigned short* Ag1 = A  + (size_t)(row0 + (c1 >> 2)) * Cc + (c1 & 3) * 8;
  const unsigned short* Bg0 = Bt + (size_t)(col0 + (c0 >> 2)) * Cc + (c0 & 3) * 8;
  const unsigned short* Bg1 = Bt + (size_t)(col0 + (c1 >> 2)) * Cc + (c1 & 3) * 8;
  char* Al0 = (char*)As + wave * 1024;
  char* Al1 = (char*)As + 4096 + wave * 1024;
  char* Bl0 = (char*)Bs + wave * 1024;
  char* Bl1 = (char*)Bs + 4096 + wave * 1024;

  for (int k0 = 0; k0 < Cc; k0 += 32) {
    __syncthreads();
    async_copy16(Al0, Ag0 + k0);
    async_copy16(Al1, Ag1 + k0);
    async_copy16(Bl0, Bg0 + k0);
    async_copy16(Bl1, Bg1 + k0);
    __syncthreads();
    bf16x8 af[4], bfr[4];
#pragma unroll
    for (int i = 0; i < 4; ++i)
      af[i] = *(const bf16x8*)(As + (wm + i * 16 + m16) * 32 + quad * 8);
#pragma unroll
    for (int j = 0; j < 4; ++j)
      bfr[j] = *(const bf16x8*)(Bs + (wn + j * 16 + m16) * 32 + quad * 8);
#pragma unroll
    for (int i = 0; i < 4; ++i)
#pragma unroll
      for (int j = 0; j < 4; ++j)
        acc[i][j] = __builtin_amdgcn_mfma_f32_16x16x32_bf16(af[i], bfr[j], acc[i][j], 0, 0, 0);
  }

#pragma unroll
  for (int i = 0; i < 4; ++i) {
    const int rbase = row0 + wm + i * 16 + quad * 4;
#pragma unroll
    for (int j = 0; j < 4; ++j) {
      const int col = col0 + wn + j * 16 + m16;
      const float bv = bias[col];
      if (MODE == 0) {
#pragma unroll
        for (int r = 0; r < 4; ++r)
          out[(size_t)(rbase + r) * Cc + col] = f2bf((acc[i][j][r] + bv) * mult);
      } else {
        const int t0 = rbase & (Tt - 1);
        const int b  = rbase >> 11;
        ushort4 pk;
        pk.x = f2bf(acc[i][j][0] + bv);
        pk.y = f2bf(acc[i][j][1] + bv);
        pk.z = f2bf(acc[i][j][2] + bv);
        pk.w = f2bf(acc[i][j][3] + bv);
        *(ushort4*)(out + (size_t)(b * Cc + col) * Tt + t0) = pk;
      }
    }
  }
}

__global__ __launch_bounds__(256) void qkv_gemm(
    const unsigned short* __restrict__ Xb,
    const unsigned short* __restrict__ Wqb, const float* __restrict__ bq,
    const unsigned short* __restrict__ Wkb, const float* __restrict__ bk,
    const unsigned short* __restrict__ Wvb, const float* __restrict__ bv,
    unsigned short* Qw, unsigned short* Kw, unsigned short* Vtw)
{
  __shared__ __align__(16) unsigned short smem[8192];
  const int z = blockIdx.z;
  // Q scale folds 1/sqrt(d) AND log2(e) so attention uses exp2 directly.
  if (z == 0)      gemm_async_body<0>(smem, smem + 4096, Xb, Wqb, bq, Qw, 0.125f * 1.44269504f);
  else if (z == 1) gemm_async_body<0>(smem, smem + 4096, Xb, Wkb, bk, Kw, 1.0f);
  else             gemm_async_body<1>(smem, smem + 4096, Xb, Wvb, bv, Vtw, 1.0f);
}

// Wave-per-strip-pair flash attention with BLOCK-SHARED, double-buffered,
// swizzled LDS staging of K/V tiles.
//   - one wave = complementary pair (sidx, 63-sidx) -> 33 tiles each;
//     phase 0 = heavy strips (63-4p-w), phase 1 = light strips (4p+w);
//     block processes a CONSTANT 34 barriered tiles: maxH=32-2p, maxL=2p+2.
//   - K/V tile staged ONCE per block via global_load_lds (traffic /4 vs r10);
//     copies for tile g+1 issued right after the barrier validating tile g
//     (one compute-tile of latency cover).
//   - swizzle: chunk (rr,ch) stages global ch^((rr>>1)&3); reader uses
//     chp=quad^((m16>>1)&3) -> 8 bank-phases for 16 lanes = 2-way = free.
__global__ __launch_bounds__(256) void attn_pair(
    const unsigned short* __restrict__ Q,
    const unsigned short* __restrict__ Kg,
    const unsigned short* __restrict__ Vt,
    unsigned short* __restrict__ Y)
{
  __shared__ __align__(16) unsigned short KV[2 * 8192];            // [buf][K 4096h | V 4096h]
  __shared__ __align__(16) unsigned short Ps[4 * 2 * 2 * 16 * PK]; // per-wave regions

  const int tid  = threadIdx.x;
  const int wave = tid >> 6;
  const int lane = tid & 63;
  const int m16  = lane & 15;
  const int quad = lane >> 4;

  const int p  = blockIdx.x;                  // 0..7
  const int bh = blockIdx.y;
  const int b = bh >> 4, h = bh & 15;

  const unsigned short* Kb = Kg + (size_t)(b * Tt) * Cc + h * Dd;
  const unsigned short* Vb = Vt + (size_t)(b * Cc + h * Dd) * Tt;
  unsigned short* PsW = Ps + (size_t)wave * (2 * 2 * 16 * PK);

  const int maxH = 32 - 2 * p;
  const int TOT  = 34;                        // maxH + (2p+2), constant
  const int chp  = quad ^ ((m16 >> 1) & 3);   // swizzled read channel

  // staging: 4 chunks/thread (2 K + 2 V); chunk cc = ii*256+tid:
  // kk=cc>>8, rr=(cc>>2)&63, ch=cc&3 -> fetch global ch^((rr>>1)&3).
  int kkS[2], rrS[2], chdS[2];
#pragma unroll
  for (int ii = 0; ii < 2; ++ii) {
    const int cc = ii * 256 + tid;
    kkS[ii]  = cc >> 8;
    rrS[ii]  = (cc >> 2) & 63;
    chdS[ii] = (cc & 3) ^ ((rrS[ii] >> 1) & 3);
  }

  // phase-0 (heavy) strip state
  int sidx = 63 - 4 * p - wave;
  int qw = sidx * 32;
  int nk = (sidx >> 1) + 1;
  bf16x8 qf[2][2];
  {
    const unsigned short* Qb = Q + (size_t)(b * Tt + qw) * Cc + h * Dd;
#pragma unroll
    for (int s = 0; s < 2; ++s)
#pragma unroll
      for (int kk = 0; kk < 2; ++kk)
        qf[s][kk] = *(const bf16x8*)(Qb + (size_t)(s * 16 + m16) * Cc + kk * 32 + quad * 8);
  }
  f32x4 o[2][4] = {};
  float lsum[2][4] = {};

  auto writeout = [&](int qw_) {
#pragma unroll
    for (int s = 0; s < 2; ++s)
#pragma unroll
      for (int r = 0; r < 4; ++r) {
        float l = lsum[s][r];
#pragma unroll
        for (int off = 1; off < 16; off <<= 1)
          l += __shfl_xor(l, off, 64);
        const float inv = (l > 0.f) ? (1.0f / l) : 0.f;
        const int t = qw_ + s * 16 + quad * 4 + r;
        unsigned short* yp = Y + (size_t)(b * Tt + t) * Cc + h * Dd;
#pragma unroll
        for (int jn = 0; jn < 4; ++jn)
          yp[jn * 16 + m16] = f2bf(o[s][jn][r] * inv);
      }
  };

  // prologue: stage tile g=0 into buf 0
  {
    char* KbufB = (char*)KV;
    char* VbufB = KbufB + 8192;
#pragma unroll
    for (int ii = 0; ii < 2; ++ii) {
      async_copy16(KbufB + ii * 4096 + wave * 1024,
                   Kb + (size_t)rrS[ii] * Cc + kkS[ii] * 32 + chdS[ii] * 8);
      async_copy16(VbufB + ii * 4096 + wave * 1024,
                   Vb + (size_t)rrS[ii] * Tt + kkS[ii] * 32 + chdS[ii] * 8);
    }
  }

  for (int g = 0; g < TOT; ++g) {
    if (g == maxH) {                          // heavy strip done -> switch to light
      writeout(qw);
      sidx = 4 * p + wave;
      qw = sidx * 32;
      nk = (sidx >> 1) + 1;
      const unsigned short* Qb = Q + (size_t)(b * Tt + qw) * Cc + h * Dd;
#pragma unroll
      for (int s = 0; s < 2; ++s)
#pragma unroll
        for (int kk = 0; kk < 2; ++kk)
          qf[s][kk] = *(const bf16x8*)(Qb + (size_t)(s * 16 + m16) * Cc + kk * 32 + quad * 8);
#pragma unroll
      for (int s = 0; s < 2; ++s)
#pragma unroll
        for (int r = 0; r < 4; ++r) {
          o[s][r >> 2][r] = 0.f;              // (zeroed fully below)
        }
#pragma unroll
      for (int s = 0; s < 2; ++s) {
#pragma unroll
        for (int jn = 0; jn < 4; ++jn)
          o[s][jn] = f32x4{0.f, 0.f, 0.f, 0.f};
#pragma unroll
        for (int r = 0; r < 4; ++r) lsum[s][r] = 0.f;
      }
    }
    const int kt  = (g < maxH) ? g : g - maxH;
    const int k0  = kt * 64;
    const int buf = g & 1;

    __syncthreads();                          // copies for g drained; prior LDS reads done
    if (g + 1 < TOT) {                        // prefetch tile g+1 into other buffer
      const int g1  = g + 1;
      const int kt1 = (g1 < maxH) ? g1 : g1 - maxH;
      const int k1  = kt1 * 64;
      char* KbufB = (char*)KV + (buf ^ 1) * 16384;
      char* VbufB = KbufB + 8192;
#pragma unroll
      for (int ii = 0; ii < 2; ++ii) {
        async_copy16(KbufB + ii * 4096 + wave * 1024,
                     Kb + (size_t)(k1 + rrS[ii]) * Cc + kkS[ii] * 32 + chdS[ii] * 8);
        async_copy16(VbufB + ii * 4096 + wave * 1024,
                     Vb + (size_t)rrS[ii] * Tt + k1 + kkS[ii] * 32 + chdS[ii] * 8);
      }
    }

    if (kt < nk) {                            // wave-uniform; barriers stay outside
      const unsigned short* Kbuf = KV + buf * 8192;
      const unsigned short* Vbuf = Kbuf + 4096;
      bf16x8 kf[2][4];
#pragma unroll
      for (int kk = 0; kk < 2; ++kk)
#pragma unroll
        for (int jn = 0; jn < 4; ++jn)
          kf[kk][jn] = *(const bf16x8*)(Kbuf + kk * 2048 + (jn * 16 + m16) * 32 + chp * 8);

#pragma unroll
      for (int s = 0; s < 2; ++s) {
        const int smin = qw + s * 16;
        if (k0 > smin + 15) continue;         // sub-strip fully masked
        f32x4 sv[4] = {};
#pragma unroll
        for (int kk = 0; kk < 2; ++kk)
#pragma unroll
          for (int jn = 0; jn < 4; ++jn)
            sv[jn] = __builtin_amdgcn_mfma_f32_16x16x32_bf16(qf[s][kk], kf[kk][jn], sv[jn], 0, 0, 0);

        if (k0 + 63 <= smin) {                // fully unmasked: bare exp2
#pragma unroll
          for (int r = 0; r < 4; ++r)
#pragma unroll
            for (int jn = 0; jn < 4; ++jn) {
              const float pv = __builtin_exp2f(sv[jn][r]);
              sv[jn][r] = pv;
              lsum[s][r] += pv;
            }
        } else {                               // diagonal: causal mask
          const int qb = smin + quad * 4;
#pragma unroll
          for (int r = 0; r < 4; ++r) {
            const int qa = qb + r;
#pragma unroll
            for (int jn = 0; jn < 4; ++jn) {
              const bool masked = (k0 + jn * 16 + m16 > qa);
              const float pv = masked ? 0.f : __builtin_exp2f(sv[jn][r]);
              sv[jn][r] = pv;
              lsum[s][r] += pv;
            }
          }
        }
        // P: C-layout -> per-wave LDS -> A-layout
#pragma unroll
        for (int jn = 0; jn < 4; ++jn)
#pragma unroll
          for (int r = 0; r < 4; ++r)
            PsW[(s * 2 + (jn >> 1)) * 16 * PK + (quad * 4 + r) * PK + (jn & 1) * 16 + m16]
                = f2bf(sv[jn][r]);
      }

      bf16x8 vf[2][4];
#pragma unroll
      for (int kk = 0; kk < 2; ++kk)
#pragma unroll
        for (int jn = 0; jn < 4; ++jn)
          vf[kk][jn] = *(const bf16x8*)(Vbuf + kk * 2048 + (jn * 16 + m16) * 32 + chp * 8);

      asm volatile("s_waitcnt lgkmcnt(0)" ::: "memory");  // Ps + vf (wave-local)
#pragma unroll
      for (int s = 0; s < 2; ++s) {
        if (k0 > qw + s * 16 + 15) continue;
        bf16x8 pf[2];
#pragma unroll
        for (int kk = 0; kk < 2; ++kk)
          pf[kk] = *(const bf16x8*)(PsW + (s * 2 + kk) * 16 * PK + m16 * PK + quad * 8);
#pragma unroll
        for (int kk = 0; kk < 2; ++kk)
#pragma unroll
          for (int jn = 0; jn < 4; ++jn)
            o[s][jn] = __builtin_amdgcn_mfma_f32_16x16x32_bf16(pf[kk], vf[kk][jn], o[s][jn], 0, 0, 0);
      }
    }
  }

  writeout(qw);                               // light strip
}

// proj: A = Yw bf16 (async staging), B = Wp f32 (register-convert), f32 out.
__global__ __launch_bounds__(256) void proj_gemm(
    const unsigned short* __restrict__ Y,
    const float* __restrict__ Wp, const float* __restrict__ bp,
    float* __restrict__ out)
{
  __shared__ __align__(16) unsigned short As[4096];
  __shared__ __align__(16) unsigned short Bs[4096];
  const int tid  = threadIdx.x;
  const int wave = tid >> 6;
  const int lane = tid & 63;
  const int m16  = lane & 15;
  const int quad = lane >> 4;
  const int row0 = blockIdx.x * 128;
  const int col0 = blockIdx.y * 128;
  const int wm = (wave >> 1) * 64;
  const int wn = (wave & 1) * 64;

  f32x4 acc[4][4] = {};

  const int c0 = tid, c1 = 256 + tid;
  const unsigned short* Ag0 = Y + (size_t)(row0 + (c0 >> 2)) * Cc + (c0 & 3) * 8;
  const unsigned short* Ag1 = Y + (size_t)(row0 + (c1 >> 2)) * Cc + (c1 & 3) * 8;
  const float* Bg0 = Wp + (size_t)(col0 + (c0 >> 2)) * Cc + (c0 & 3) * 8;
  const float* Bg1 = Wp + (size_t)(col0 + (c1 >> 2)) * Cc + (c1 & 3) * 8;
  char* Al0 = (char*)As + wave * 1024;
  char* Al1 = (char*)As + 4096 + wave * 1024;

  uint4 b0 = ldconv_f32(Bg0);
  uint4 b1 = ldconv_f32(Bg1);

  for (int k0 = 0; k0 < Cc; k0 += 32) {
    __syncthreads();
    async_copy16(Al0, Ag0 + k0);
    async_copy16(Al1, Ag1 + k0);
    *(uint4*)(Bs + (size_t)c0 * 8) = b0;
    *(uint4*)(Bs + (size_t)c1 * 8) = b1;
    __syncthreads();
    if (k0 + 32 < Cc) {
      b0 = ldconv_f32(Bg0 + k0 + 32);
      b1 = ldconv_f32(Bg1 + k0 + 32);
    }
    bf16x8 af[4], bfr[4];
#pragma unroll
    for (int i = 0; i < 4; ++i)
      af[i] = *(const bf16x8*)(As + (wm + i * 16 + m16) * 32 + quad * 8);
#pragma unroll
    for (int j = 0; j < 4; ++j)
      bfr[j] = *(const bf16x8*)(Bs + (wn + j * 16 + m16) * 32 + quad * 8);
#pragma unroll
    for (int i = 0; i < 4; ++i)
#pragma unroll
      for (int j = 0; j < 4; ++j)
        acc[i][j] = __builtin_amdgcn_mfma_f32_16x16x32_bf16(af[i], bfr[j], acc[i][j], 0, 0, 0);
  }

#pragma unroll
  for (int i = 0; i < 4; ++i) {
    const int rbase = row0 + wm + i * 16 + quad * 4;
#pragma unroll
    for (int j = 0; j < 4; ++j) {
      const int col = col0 + wn + j * 16 + m16;
      const float bv = bp[col];
#pragma unroll
      for (int r = 0; r < 4; ++r)
        out[(size_t)(rbase + r) * Cc + col] = acc[i][j][r] + bv;
    }
  }
}

extern "C" void kernel_launch(void* const* d_in, const int* in_sizes, int n_in,
                              void* d_out, int out_size, void* d_ws, size_t ws_size,
                              hipStream_t stream)
{
  const float* x  = (const float*)d_in[0];
  const float* Wq = (const float*)d_in[1];
  const float* bq = (const float*)d_in[2];
  const float* Wk = (const float*)d_in[3];
  const float* bk = (const float*)d_in[4];
  const float* Wv = (const float*)d_in[5];
  const float* bv = (const float*)d_in[6];
  const float* Wp = (const float*)d_in[7];
  const float* bp = (const float*)d_in[8];

  unsigned short* ws  = (unsigned short*)d_ws;
  unsigned short* Qw  = ws;                          // bf16 [8192][1024] (scale folded)
  unsigned short* Kw  = ws + (size_t)1 * XN;         // bf16 [8192][1024]
  unsigned short* Vtw = ws + (size_t)2 * XN;         // bf16 [b*1024 + n][2048]
  unsigned short* Yw  = ws + (size_t)3 * XN;         // bf16 [8192][1024]

  // d_out doubles as bf16 scratch for converted X/Wq/Wk/Wv; proj overwrites last.
  unsigned short* cvt = (unsigned short*)d_out;
  unsigned short* Xb  = cvt;
  unsigned short* Wqb = cvt + XN;
  unsigned short* Wkb = cvt + XN + WN;
  unsigned short* Wvb = cvt + XN + 2 * WN;
  float* out = (float*)d_out;

  convert_all<<<5632, 256, 0, stream>>>(x, Wq, Wk, Wv, cvt);
  qkv_gemm<<<dim3(64, 8, 3), 256, 0, stream>>>(Xb, Wqb, bq, Wkb, bk, Wvb, bv, Qw, Kw, Vtw);
  attn_pair<<<dim3(8, 64), 256, 0, stream>>>(Qw, Kw, Vtw, Yw);
  proj_gemm<<<dim3(64, 8), 256, 0, stream>>>(Yw, Wp, bp, out);
}

// Round 12
// 305.381 us; speedup vs baseline: 1.7435x; 1.0392x over previous
//
#include <hip/hip_runtime.h>
#include <hip/hip_bf16.h>

typedef __attribute__((ext_vector_type(8))) short bf16x8;
typedef __attribute__((ext_vector_type(4))) float f32x4;

static constexpr int Tt = 2048;   // seq len
static constexpr int Cc = 1024;   // channels
static constexpr int Dd = 64;     // head dim
static constexpr int Mm = 8192;   // B*T

static constexpr size_t XN = (size_t)Mm * Cc;   // 8388608
static constexpr size_t WN = (size_t)Cc * Cc;   // 1048576

__device__ __forceinline__ void async_copy16(void* lds, const void* g) {
  __builtin_amdgcn_global_load_lds(
      (const __attribute__((address_space(1))) void*)g,
      (__attribute__((address_space(3))) void*)lds, 16, 0, 0);
}

__device__ __forceinline__ unsigned short f2bf(float f) {
  union { float f; unsigned int u; } v; v.f = f;
  unsigned int r = (v.u + 0x7fffu + ((v.u >> 16) & 1u)) >> 16;
  return (unsigned short)r;
}
__device__ __forceinline__ unsigned int pack2bf(float f0, float f1) {
  unsigned int b0 = __float_as_uint(f0) + 0x8000u;
  unsigned int b1 = __float_as_uint(f1) + 0x8000u;
  return (b1 & 0xffff0000u) | (b0 >> 16);
}
__device__ __forceinline__ uint4 ldconv_f32(const float* p) {
  float4 lo = *(const float4*)p;
  float4 hi = *(const float4*)(p + 4);
  uint4 r;
  r.x = pack2bf(lo.x, lo.y);
  r.y = pack2bf(lo.z, lo.w);
  r.z = pack2bf(hi.x, hi.y);
  r.w = pack2bf(hi.z, hi.w);
  return r;
}

// f32 -> bf16 pre-convert of X, Wq, Wk, Wv into d_out scratch (23.1MB < 33.5MB).
__global__ __launch_bounds__(256) void convert_all(
    const float* __restrict__ x, const float* __restrict__ wq,
    const float* __restrict__ wk, const float* __restrict__ wv,
    unsigned short* __restrict__ dst)
{
  const size_t i = ((size_t)blockIdx.x * 256 + threadIdx.x) * 8;
  const float* s; size_t off;
  if (i < XN)                { s = x;  off = 0; }
  else if (i < XN + WN)      { s = wq; off = XN; }
  else if (i < XN + 2 * WN)  { s = wk; off = XN + WN; }
  else                       { s = wv; off = XN + 2 * WN; }
  *(uint4*)(dst + i) = ldconv_f32(s + (i - off));
}

// NT GEMM, all-bf16 inputs, m97-pattern global_load_lds staging.
// MODE 0: bf16 out[m*Cc+n]*mult+bias. MODE 1 (V): bf16 out[(b*Cc+n)*Tt+t].
template <int MODE>
__device__ __forceinline__ void gemm_async_body(
    unsigned short* As, unsigned short* Bs,
    const unsigned short* __restrict__ A,
    const unsigned short* __restrict__ Bt,
    const float* __restrict__ bias,
    unsigned short* __restrict__ out, float mult)
{
  const int tid  = threadIdx.x;
  const int wave = tid >> 6;
  const int lane = tid & 63;
  const int m16  = lane & 15;
  const int quad = lane >> 4;
  const int row0 = blockIdx.x * 128;
  const int col0 = blockIdx.y * 128;
  const int wm = (wave >> 1) * 64;
  const int wn = (wave & 1) * 64;

  f32x4 acc[4][4] = {};

  const int c0 = tid, c1 = 256 + tid;
  const unsigned short* Ag0 = A  + (size_t)(row0 + (c0 >> 2)) * Cc + (c0 & 3) * 8;
  const unsigned short* Ag1 = A  + (size_t)(row0 + (c1 >> 2)) * Cc + (c1 & 3) * 8;
  const unsigned short* Bg0 = Bt + (size_t)(col0 + (c0 >> 2)) * Cc + (c0 & 3) * 8;
  const unsigned short* Bg1 = Bt + (size_t)(col0 + (c1 >> 2)) * Cc + (c1 & 3) * 8;
  char* Al0 = (char*)As + wave * 1024;
  char* Al1 = (char*)As + 4096 + wave * 1024;
  char* Bl0 = (char*)Bs + wave * 1024;
  char* Bl1 = (char*)Bs + 4096 + wave * 1024;

  for (int k0 = 0; k0 < Cc; k0 += 32) {
    __syncthreads();
    async_copy16(Al0, Ag0 + k0);
    async_copy16(Al1, Ag1 + k0);
    async_copy16(Bl0, Bg0 + k0);
    async_copy16(Bl1, Bg1 + k0);
    __syncthreads();
    bf16x8 af[4], bfr[4];
#pragma unroll
    for (int i = 0; i < 4; ++i)
      af[i] = *(const bf16x8*)(As + (wm + i * 16 + m16) * 32 + quad * 8);
#pragma unroll
    for (int j = 0; j < 4; ++j)
      bfr[j] = *(const bf16x8*)(Bs + (wn + j * 16 + m16) * 32 + quad * 8);
#pragma unroll
    for (int i = 0; i < 4; ++i)
#pragma unroll
      for (int j = 0; j < 4; ++j)
        acc[i][j] = __builtin_amdgcn_mfma_f32_16x16x32_bf16(af[i], bfr[j], acc[i][j], 0, 0, 0);
  }

#pragma unroll
  for (int i = 0; i < 4; ++i) {
    const int rbase = row0 + wm + i * 16 + quad * 4;
#pragma unroll
    for (int j = 0; j < 4; ++j) {
      const int col = col0 + wn + j * 16 + m16;
      const float bv = bias[col];
      if (MODE == 0) {
#pragma unroll
        for (int r = 0; r < 4; ++r)
          out[(size_t)(rbase + r) * Cc + col] = f2bf((acc[i][j][r] + bv) * mult);
      } else {
        const int t0 = rbase & (Tt - 1);
        const int b  = rbase >> 11;
        ushort4 pk;
        pk.x = f2bf(acc[i][j][0] + bv);
        pk.y = f2bf(acc[i][j][1] + bv);
        pk.z = f2bf(acc[i][j][2] + bv);
        pk.w = f2bf(acc[i][j][3] + bv);
        *(ushort4*)(out + (size_t)(b * Cc + col) * Tt + t0) = pk;
      }
    }
  }
}

__global__ __launch_bounds__(256) void qkv_gemm(
    const unsigned short* __restrict__ Xb,
    const unsigned short* __restrict__ Wqb, const float* __restrict__ bq,
    const unsigned short* __restrict__ Wkb, const float* __restrict__ bk,
    const unsigned short* __restrict__ Wvb, const float* __restrict__ bv,
    unsigned short* Qw, unsigned short* Kw, unsigned short* Vtw)
{
  __shared__ __align__(16) unsigned short smem[8192];
  const int z = blockIdx.z;
  // Q scale folds 1/sqrt(d) AND log2(e) so attention uses exp2 directly.
  if (z == 0)      gemm_async_body<0>(smem, smem + 4096, Xb, Wqb, bq, Qw, 0.125f * 1.44269504f);
  else if (z == 1) gemm_async_body<0>(smem, smem + 4096, Xb, Wkb, bk, Kw, 1.0f);
  else             gemm_async_body<1>(smem, smem + 4096, Xb, Wvb, bv, Vtw, 1.0f);
}

// Wave-per-strip-pair flash attention, TRANSPOSED algebra:
//   S^T = K.Q^T (C-layout: col=q on m16, row=key=quad*4+r per 16-block jn)
//   O^T = V^T.P^T (Vt rows ARE the V^T A-operand; P^T B-frag built by pure
//   in-register redistribution: word w of ptf[kk] = P2[2kk+(quad>>1)][w&1]
//   from lane m16 + 32*(quad&1) + 16*(w>>1))  -> NO Ps LDS round-trip.
// Block-shared double-buffered swizzled K/V staging (as r11); per-wave pair
// (sidx, 63-sidx) = 33 tiles; block = const 34 barriered tiles.
__global__ __launch_bounds__(256) void attn_pair(
    const unsigned short* __restrict__ Q,
    const unsigned short* __restrict__ Kg,
    const unsigned short* __restrict__ Vt,
    unsigned short* __restrict__ Y)
{
  __shared__ __align__(16) unsigned short KV[2 * 8192];  // [buf][K 4096h | V 4096h]

  const int tid  = threadIdx.x;
  const int wave = tid >> 6;
  const int lane = tid & 63;
  const int m16  = lane & 15;
  const int quad = lane >> 4;

  const int p  = blockIdx.x;                  // 0..7
  const int bh = blockIdx.y;
  const int b = bh >> 4, h = bh & 15;

  const unsigned short* Kb = Kg + (size_t)(b * Tt) * Cc + h * Dd;
  const unsigned short* Vb = Vt + (size_t)(b * Cc + h * Dd) * Tt;

  const int maxH = 32 - 2 * p;
  const int TOT  = 34;                        // maxH + (2p+2), constant
  const int chp  = quad ^ ((m16 >> 1) & 3);   // swizzled read channel
  const int slA  = m16 + ((quad & 1) << 5);   // P^T shuffle source lanes
  const int slB  = slA + 16;
  const int hi   = quad >> 1;                 // selects jn' = 2kk + hi

  int kkS[2], rrS[2], chdS[2];
#pragma unroll
  for (int ii = 0; ii < 2; ++ii) {
    const int cc = ii * 256 + tid;
    kkS[ii]  = cc >> 8;
    rrS[ii]  = (cc >> 2) & 63;
    chdS[ii] = (cc & 3) ^ ((rrS[ii] >> 1) & 3);
  }

  // phase-0 (heavy) strip state
  int sidx = 63 - 4 * p - wave;
  int qw = sidx * 32;
  int nk = (sidx >> 1) + 1;
  bf16x8 qf[2][2];
  {
    const unsigned short* Qb = Q + (size_t)(b * Tt + qw) * Cc + h * Dd;
#pragma unroll
    for (int s = 0; s < 2; ++s)
#pragma unroll
      for (int kk = 0; kk < 2; ++kk)
        qf[s][kk] = *(const bf16x8*)(Qb + (size_t)(s * 16 + m16) * Cc + kk * 32 + quad * 8);
  }
  f32x4 o[2][4] = {};
  float lsum[2] = {};

  auto writeout = [&](int qw_) {
#pragma unroll
    for (int s = 0; s < 2; ++s) {
      float l = lsum[s];
      l += __shfl_xor(l, 16, 64);
      l += __shfl_xor(l, 32, 64);
      const float inv = (l > 0.f) ? (1.0f / l) : 0.f;
      const int t = qw_ + s * 16 + m16;
      unsigned short* yp = Y + (size_t)(b * Tt + t) * Cc + h * Dd + quad * 4;
#pragma unroll
      for (int jn = 0; jn < 4; ++jn) {
        ushort4 pk;
        pk.x = f2bf(o[s][jn][0] * inv);
        pk.y = f2bf(o[s][jn][1] * inv);
        pk.z = f2bf(o[s][jn][2] * inv);
        pk.w = f2bf(o[s][jn][3] * inv);
        *(ushort4*)(yp + jn * 16) = pk;
      }
    }
  };

  // prologue: stage tile g=0 into buf 0
  {
    char* KbufB = (char*)KV;
    char* VbufB = KbufB + 8192;
#pragma unroll
    for (int ii = 0; ii < 2; ++ii) {
      async_copy16(KbufB + ii * 4096 + wave * 1024,
                   Kb + (size_t)rrS[ii] * Cc + kkS[ii] * 32 + chdS[ii] * 8);
      async_copy16(VbufB + ii * 4096 + wave * 1024,
                   Vb + (size_t)rrS[ii] * Tt + kkS[ii] * 32 + chdS[ii] * 8);
    }
  }

  for (int g = 0; g < TOT; ++g) {
    if (g == maxH) {                          // heavy strip done -> switch to light
      writeout(qw);
      sidx = 4 * p + wave;
      qw = sidx * 32;
      nk = (sidx >> 1) + 1;
      const unsigned short* Qb = Q + (size_t)(b * Tt + qw) * Cc + h * Dd;
#pragma unroll
      for (int s = 0; s < 2; ++s) {
#pragma unroll
        for (int kk = 0; kk < 2; ++kk)
          qf[s][kk] = *(const bf16x8*)(Qb + (size_t)(s * 16 + m16) * Cc + kk * 32 + quad * 8);
#pragma unroll
        for (int jn = 0; jn < 4; ++jn)
          o[s][jn] = f32x4{0.f, 0.f, 0.f, 0.f};
        lsum[s] = 0.f;
      }
    }
    const int kt  = (g < maxH) ? g : g - maxH;
    const int k0  = kt * 64;
    const int buf = g & 1;

    __syncthreads();                          // copies for g drained; prior LDS reads done
    if (g + 1 < TOT) {                        // prefetch tile g+1 into other buffer
      const int g1  = g + 1;
      const int kt1 = (g1 < maxH) ? g1 : g1 - maxH;
      const int k1  = kt1 * 64;
      char* KbufB = (char*)KV + (buf ^ 1) * 16384;
      char* VbufB = KbufB + 8192;
#pragma unroll
      for (int ii = 0; ii < 2; ++ii) {
        async_copy16(KbufB + ii * 4096 + wave * 1024,
                     Kb + (size_t)(k1 + rrS[ii]) * Cc + kkS[ii] * 32 + chdS[ii] * 8);
        async_copy16(VbufB + ii * 4096 + wave * 1024,
                     Vb + (size_t)rrS[ii] * Tt + k1 + kkS[ii] * 32 + chdS[ii] * 8);
      }
    }

    if (kt < nk) {                            // wave-uniform; barriers stay outside
      const unsigned short* Kbuf = KV + buf * 8192;
      const unsigned short* Vbuf = Kbuf + 4096;
      bf16x8 kf[2][4], vf[2][4];
#pragma unroll
      for (int kk = 0; kk < 2; ++kk)
#pragma unroll
        for (int jn = 0; jn < 4; ++jn) {
          kf[kk][jn] = *(const bf16x8*)(Kbuf + kk * 2048 + (jn * 16 + m16) * 32 + chp * 8);
          vf[kk][jn] = *(const bf16x8*)(Vbuf + kk * 2048 + (jn * 16 + m16) * 32 + chp * 8);
        }

#pragma unroll
      for (int s = 0; s < 2; ++s) {
        const int smin = qw + s * 16;
        if (k0 > smin + 15) continue;         // sub-strip fully masked
        // S^T = K.Q^T : C-layout lane m16 = q, reg (jn,r) = key jn*16+quad*4+r
        f32x4 sv[4] = {};
#pragma unroll
        for (int kk = 0; kk < 2; ++kk)
#pragma unroll
          for (int jn = 0; jn < 4; ++jn)
            sv[jn] = __builtin_amdgcn_mfma_f32_16x16x32_bf16(kf[kk][jn], qf[s][kk], sv[jn], 0, 0, 0);

        if (k0 + 63 <= smin) {                // fully unmasked: bare exp2
#pragma unroll
          for (int jn = 0; jn < 4; ++jn)
#pragma unroll
            for (int r = 0; r < 4; ++r) {
              const float pv = __builtin_exp2f(sv[jn][r]);
              sv[jn][r] = pv;
              lsum[s] += pv;
            }
        } else {                               // diagonal: causal mask
          const int qcol = smin + m16;
#pragma unroll
          for (int jn = 0; jn < 4; ++jn)
#pragma unroll
            for (int r = 0; r < 4; ++r) {
              const bool masked = (k0 + jn * 16 + quad * 4 + r > qcol);
              const float pv = masked ? 0.f : __builtin_exp2f(sv[jn][r]);
              sv[jn][r] = pv;
              lsum[s] += pv;
            }
        }
        // pack key-pairs, redistribute to P^T B-fragments (in-register)
        unsigned int P2[4][2];
#pragma unroll
        for (int jn = 0; jn < 4; ++jn) {
          P2[jn][0] = pack2bf(sv[jn][0], sv[jn][1]);
          P2[jn][1] = pack2bf(sv[jn][2], sv[jn][3]);
        }
#pragma unroll
        for (int kk = 0; kk < 2; ++kk) {
          const int a0 = __shfl((int)P2[2 * kk][0],     slA, 64);
          const int b0 = __shfl((int)P2[2 * kk + 1][0], slA, 64);
          const int a1 = __shfl((int)P2[2 * kk][1],     slA, 64);
          const int b1 = __shfl((int)P2[2 * kk + 1][1], slA, 64);
          const int a2 = __shfl((int)P2[2 * kk][0],     slB, 64);
          const int b2 = __shfl((int)P2[2 * kk + 1][0], slB, 64);
          const int a3 = __shfl((int)P2[2 * kk][1],     slB, 64);
          const int b3 = __shfl((int)P2[2 * kk + 1][1], slB, 64);
          uint4 u;
          u.x = (unsigned int)(hi ? b0 : a0);
          u.y = (unsigned int)(hi ? b1 : a1);
          u.z = (unsigned int)(hi ? b2 : a2);
          u.w = (unsigned int)(hi ? b3 : a3);
          union { uint4 u4; bf16x8 bf; } cv; cv.u4 = u;
          // O^T += V^T . P^T  (A = Vt rows d, B = P^T)
#pragma unroll
          for (int jn = 0; jn < 4; ++jn)
            o[s][jn] = __builtin_amdgcn_mfma_f32_16x16x32_bf16(vf[kk][jn], cv.bf, o[s][jn], 0, 0, 0);
        }
      }
    }
  }

  writeout(qw);                               // light strip
}

// proj: A = Yw bf16 (async staging), B = Wp f32 (register-convert), f32 out.
__global__ __launch_bounds__(256) void proj_gemm(
    const unsigned short* __restrict__ Y,
    const float* __restrict__ Wp, const float* __restrict__ bp,
    float* __restrict__ out)
{
  __shared__ __align__(16) unsigned short As[4096];
  __shared__ __align__(16) unsigned short Bs[4096];
  const int tid  = threadIdx.x;
  const int wave = tid >> 6;
  const int lane = tid & 63;
  const int m16  = lane & 15;
  const int quad = lane >> 4;
  const int row0 = blockIdx.x * 128;
  const int col0 = blockIdx.y * 128;
  const int wm = (wave >> 1) * 64;
  const int wn = (wave & 1) * 64;

  f32x4 acc[4][4] = {};

  const int c0 = tid, c1 = 256 + tid;
  const unsigned short* Ag0 = Y + (size_t)(row0 + (c0 >> 2)) * Cc + (c0 & 3) * 8;
  const unsigned short* Ag1 = Y + (size_t)(row0 + (c1 >> 2)) * Cc + (c1 & 3) * 8;
  const float* Bg0 = Wp + (size_t)(col0 + (c0 >> 2)) * Cc + (c0 & 3) * 8;
  const float* Bg1 = Wp + (size_t)(col0 + (c1 >> 2)) * Cc + (c1 & 3) * 8;
  char* Al0 = (char*)As + wave * 1024;
  char* Al1 = (char*)As + 4096 + wave * 1024;

  uint4 b0 = ldconv_f32(Bg0);
  uint4 b1 = ldconv_f32(Bg1);

  for (int k0 = 0; k0 < Cc; k0 += 32) {
    __syncthreads();
    async_copy16(Al0, Ag0 + k0);
    async_copy16(Al1, Ag1 + k0);
    *(uint4*)(Bs + (size_t)c0 * 8) = b0;
    *(uint4*)(Bs + (size_t)c1 * 8) = b1;
    __syncthreads();
    if (k0 + 32 < Cc) {
      b0 = ldconv_f32(Bg0 + k0 + 32);
      b1 = ldconv_f32(Bg1 + k0 + 32);
    }
    bf16x8 af[4], bfr[4];
#pragma unroll
    for (int i = 0; i < 4; ++i)
      af[i] = *(const bf16x8*)(As + (wm + i * 16 + m16) * 32 + quad * 8);
#pragma unroll
    for (int j = 0; j < 4; ++j)
      bfr[j] = *(const bf16x8*)(Bs + (wn + j * 16 + m16) * 32 + quad * 8);
#pragma unroll
    for (int i = 0; i < 4; ++i)
#pragma unroll
      for (int j = 0; j < 4; ++j)
        acc[i][j] = __builtin_amdgcn_mfma_f32_16x16x32_bf16(af[i], bfr[j], acc[i][j], 0, 0, 0);
  }

#pragma unroll
  for (int i = 0; i < 4; ++i) {
    const int rbase = row0 + wm + i * 16 + quad * 4;
#pragma unroll
    for (int j = 0; j < 4; ++j) {
      const int col = col0 + wn + j * 16 + m16;
      const float bv = bp[col];
#pragma unroll
      for (int r = 0; r < 4; ++r)
        out[(size_t)(rbase + r) * Cc + col] = acc[i][j][r] + bv;
    }
  }
}

extern "C" void kernel_launch(void* const* d_in, const int* in_sizes, int n_in,
                              void* d_out, int out_size, void* d_ws, size_t ws_size,
                              hipStream_t stream)
{
  const float* x  = (const float*)d_in[0];
  const float* Wq = (const float*)d_in[1];
  const float* bq = (const float*)d_in[2];
  const float* Wk = (const float*)d_in[3];
  const float* bk = (const float*)d_in[4];
  const float* Wv = (const float*)d_in[5];
  const float* bv = (const float*)d_in[6];
  const float* Wp = (const float*)d_in[7];
  const float* bp = (const float*)d_in[8];

  unsigned short* ws  = (unsigned short*)d_ws;
  unsigned short* Qw  = ws;                          // bf16 [8192][1024] (scale folded)
  unsigned short* Kw  = ws + (size_t)1 * XN;         // bf16 [8192][1024]
  unsigned short* Vtw = ws + (size_t)2 * XN;         // bf16 [b*1024 + n][2048]
  unsigned short* Yw  = ws + (size_t)3 * XN;         // bf16 [8192][1024]

  // d_out doubles as bf16 scratch for converted X/Wq/Wk/Wv; proj overwrites last.
  unsigned short* cvt = (unsigned short*)d_out;
  unsigned short* Xb  = cvt;
  unsigned short* Wqb = cvt + XN;
  unsigned short* Wkb = cvt + XN + WN;
  unsigned short* Wvb = cvt + XN + 2 * WN;
  float* out = (float*)d_out;

  convert_all<<<5632, 256, 0, stream>>>(x, Wq, Wk, Wv, cvt);
  qkv_gemm<<<dim3(64, 8, 3), 256, 0, stream>>>(Xb, Wqb, bq, Wkb, bk, Wvb, bv, Qw, Kw, Vtw);
  attn_pair<<<dim3(8, 64), 256, 0, stream>>>(Qw, Kw, Vtw, Yw);
  proj_gemm<<<dim3(64, 8), 256, 0, stream>>>(Yw, Wp, bp, out);
}